// Round 9
// baseline (252.798 us; speedup 1.0000x reference)
//
#include <hip/hip_runtime.h>

// GraphNetworkLayer: B=8, N=4096, E=16384, G=64, D=128, fp32 in/out.
// Round 9: structural (uncancellable) prefetch in the MFMA kernels.
//  - B: whole per-block weight half (64KB edge / 48KB node) async-staged to
//    LDS once via global_load_lds_dwordx4 (no staging VGPRs, no ds_writes).
//    Bank-conflict swizzle is baked into the GLOBAL image (prep_w emits
//    WeT2/WnT2 pre-swizzled: img[row*RS + t] = B[row][t ^ ((row&7)<<4)]),
//    LDS staging is linear, ds_read applies the same XOR (rule-21 pattern).
//  - A: ALL K-segments' gathers issued before the single __syncthreads();
//    its vmcnt(0) drain makes everything resident, then the K-loop is pure
//    ds_read_b128 + MFMA with no barriers and no global loads.
//  - Swapped mfma(B,A,acc) epilogue (float4 stores) from R8, validated.
// Rest of pipeline identical to R8. No float atomics anywhere.

#define DD 128
typedef unsigned short u16;
typedef __attribute__((ext_vector_type(8))) short short8;   // 8 bf16
typedef __attribute__((ext_vector_type(4))) float f32x4;

constexpr int B_ = 8, N_ = 4096, E_ = 16384, G_ = 64;
constexpr int NODES_SZ = B_ * N_ * DD;   // 4,194,304
constexpr int EDGES_SZ = B_ * E_ * DD;   // 16,777,216
constexpr int BE_ = B_ * E_;             // 131,072
constexpr int BN_ = B_ * N_;             // 32,768
constexpr int BG_ = B_ * G_;             // 512
constexpr int GLOB_SZ = BG_ * DD;        // 65,536
constexpr int PART = 8;

constexpr int OFF_NODES = 0;
constexpr int OFF_EDGES = OFF_NODES + NODES_SZ;
constexpr int OFF_RECV  = OFF_EDGES + EDGES_SZ;
constexpr int OFF_SEND  = OFF_RECV + BE_;
constexpr int OFF_GLOB  = OFF_SEND + BE_;
constexpr int OFF_NGI   = OFF_GLOB + GLOB_SZ;
constexpr int OFF_EGI   = OFF_NGI + BN_;

// ws layout (float-element offsets)
constexpr int WS_EAGGP = 0;                          // [PART][BG][DD] f32
constexpr int WS_NAGGP = WS_EAGGP + PART * GLOB_SZ;  // [PART][BG][DD] f32
constexpr int WS_CNT   = WS_NAGGP + PART * GLOB_SZ;  // int [B*N] (zeroed)
constexpr int WS_GCNTE = WS_CNT + BN_;               // int [512] (zeroed)
constexpr int WS_GCNTN = WS_GCNTE + 512;             // int [512] (zeroed)
constexpr int WS_CUR   = WS_GCNTN + 512;             // int [B*N]
constexpr int WS_GCURE = WS_CUR + BN_;               // int [512]
constexpr int WS_GCURN = WS_GCURE + 512;             // int [512]
constexpr int WS_ELIST = WS_GCURN + 512;             // int [B*E]
constexpr int WS_GELE  = WS_ELIST + BE_;             // int [B*E]
constexpr int WS_GELN  = WS_GELE + BE_;              // int [B*N]
constexpr int WS_ADJB  = WS_GELN + BN_;              // u16 [B,N,D]
constexpr int WS_NODB  = WS_ADJB + (BN_ * DD) / 2;   // u16 [B,N,D]
constexpr int WS_GLOBB = WS_NODB + (BN_ * DD) / 2;   // u16 [B,G,D]
constexpr int WS_WET   = WS_GLOBB + GLOB_SZ / 2;     // u16 [128*512] swz image
constexpr int WS_WNT   = WS_WET + 32768;             // u16 [128*384] swz image

__device__ inline u16 f2bf(float f) {
    union { float f; unsigned u; } v; v.f = f;
    return (u16)((v.u + 0x7fffu + ((v.u >> 16) & 1u)) >> 16);
}
__device__ inline short8 pack8(float4 a, float4 b) {
    short8 r;
    r[0] = (short)f2bf(a.x); r[1] = (short)f2bf(a.y);
    r[2] = (short)f2bf(a.z); r[3] = (short)f2bf(a.w);
    r[4] = (short)f2bf(b.x); r[5] = (short)f2bf(b.y);
    r[6] = (short)f2bf(b.z); r[7] = (short)f2bf(b.w);
    return r;
}

// pre-swizzled B images:
// WeT2[ch*32768 + r] : a2=r*2, row=a2>>10, inb=a2&1023, kb=inb^((row&7)<<4)
//   value = bf16(We[(kb>>1)*128 + ch*64 + row])
// WnT2[ch*24576 + r] : row=r/384, inb=(r%384)*2, kb=inb^((row&7)<<4)
//   value = bf16(Wn[(kb>>1)*128 + ch*64 + row])
__global__ __launch_bounds__(256) void prep_w(
    const float* __restrict__ We, const float* __restrict__ Wn,
    u16* __restrict__ WeT2, u16* __restrict__ WnT2) {
    const int i = blockIdx.x * blockDim.x + threadIdx.x;
    if (i < 65536) {
        const int ch = i >> 15;
        const int r = i & 32767;
        const int row = r >> 9;
        const int inb = (r << 1) & 1023;
        const int kb = inb ^ ((row & 7) << 4);
        WeT2[i] = f2bf(We[(kb >> 1) * DD + ch * 64 + row]);
    } else {
        const int q = i - 65536;
        if (q < 49152) {
            const int ch = q / 24576;
            const int r = q % 24576;
            const int row = r / 384;
            const int inb = (r % 384) << 1;
            const int kb = inb ^ ((row & 7) << 4);
            WnT2[q] = f2bf(Wn[(kb >> 1) * DD + ch * 64 + row]);
        }
    }
}

__global__ __launch_bounds__(256) void cast_bf16(
    const float* __restrict__ nodes, const float* __restrict__ glob,
    u16* __restrict__ nodesB, u16* __restrict__ globB) {
    const int i = blockIdx.x * 256 + threadIdx.x;
    const int NT = NODES_SZ / 8;
    if (i < NT) {
        const float4 a = *(const float4*)(nodes + (long)i * 8);
        const float4 b = *(const float4*)(nodes + (long)i * 8 + 4);
        *(short8*)(nodesB + (long)i * 8) = pack8(a, b);
    } else {
        const int j = i - NT;
        const float4 a = *(const float4*)(glob + (long)j * 8);
        const float4 b = *(const float4*)(glob + (long)j * 8 + 4);
        *(short8*)(globB + (long)j * 8) = pack8(a, b);
    }
}

__global__ __launch_bounds__(256) void init_misc(
    const int* __restrict__ recv, const int* __restrict__ send,
    const int* __restrict__ ngi, const int* __restrict__ egi,
    float* __restrict__ out, int* __restrict__ zbase) {
    const int i = blockIdx.x * 256 + threadIdx.x;
    const int total = 3 * BE_ + BN_;
    if (i < total) {
        if (i < BE_)                 out[OFF_RECV + i] = (float)recv[i];
        else if (i < 2 * BE_)        out[OFF_SEND + (i - BE_)] = (float)send[i - BE_];
        else if (i < 2 * BE_ + BN_)  out[OFF_NGI + (i - 2 * BE_)] = (float)ngi[i - 2 * BE_];
        else                         out[OFF_EGI + (i - 2 * BE_ - BN_)] = (float)egi[i - 2 * BE_ - BN_];
    } else {
        const int j = i - total;
        if (j < BN_ + 1024) zbase[j] = 0;
    }
}

__global__ __launch_bounds__(256) void k_hist_all(
    const int* __restrict__ recv, const int* __restrict__ egi,
    const int* __restrict__ ngi,
    int* __restrict__ cnt, int* __restrict__ gcnt_e, int* __restrict__ gcnt_n) {
    const int i = blockIdx.x * 256 + threadIdx.x;
    const int b = i >> 14;
    atomicAdd(&cnt[b * N_ + recv[i]], 1);
    atomicAdd(&gcnt_e[b * G_ + egi[i]], 1);
    if (i < BN_) atomicAdd(&gcnt_n[(i >> 12) * G_ + ngi[i]], 1);
}

__global__ __launch_bounds__(1024) void k_scan(
    const int* __restrict__ cnt, int* __restrict__ cur,
    const int* __restrict__ gcnt_e, int* __restrict__ gcur_e,
    const int* __restrict__ gcnt_n, int* __restrict__ gcur_n) {
    __shared__ int s[1024];
    const int b = blockIdx.x;
    const int t = threadIdx.x;
    const int base = b * N_;
    int c[4];
    int sum = 0;
    #pragma unroll
    for (int i = 0; i < 4; ++i) { c[i] = cnt[base + 4 * t + i]; sum += c[i]; }
    s[t] = sum;
    __syncthreads();
    for (int off = 1; off < 1024; off <<= 1) {
        int v = s[t];
        if (t >= off) v += s[t - off];
        __syncthreads();
        s[t] = v;
        __syncthreads();
    }
    int eb = s[t] - sum;
    #pragma unroll
    for (int i = 0; i < 4; ++i) { cur[base + 4 * t + i] = eb; eb += c[i]; }
    __syncthreads();
    int gv = 0;
    if (t < G_) { gv = gcnt_e[b * G_ + t]; s[t] = gv; }
    __syncthreads();
    for (int off = 1; off < G_; off <<= 1) {
        int v = 0;
        if (t < G_) { v = s[t]; if (t >= off) v += s[t - off]; }
        __syncthreads();
        if (t < G_) s[t] = v;
        __syncthreads();
    }
    if (t < G_) gcur_e[b * G_ + t] = s[t] - gv;
    __syncthreads();
    if (t < G_) { gv = gcnt_n[b * G_ + t]; s[t] = gv; }
    __syncthreads();
    for (int off = 1; off < G_; off <<= 1) {
        int v = 0;
        if (t < G_) { v = s[t]; if (t >= off) v += s[t - off]; }
        __syncthreads();
        if (t < G_) s[t] = v;
        __syncthreads();
    }
    if (t < G_) gcur_n[b * G_ + t] = s[t] - gv;
}

__global__ __launch_bounds__(256) void k_fill_all(
    const int* __restrict__ recv, const int* __restrict__ egi,
    const int* __restrict__ ngi,
    int* __restrict__ cur, int* __restrict__ elist,
    int* __restrict__ gcur_e, int* __restrict__ gelist_e,
    int* __restrict__ gcur_n, int* __restrict__ gelist_n) {
    const int i = blockIdx.x * 256 + threadIdx.x;
    const int b = i >> 14;
    const int s1 = atomicAdd(&cur[b * N_ + recv[i]], 1);
    elist[b * E_ + s1] = i;
    const int s2 = atomicAdd(&gcur_e[b * G_ + egi[i]], 1);
    gelist_e[b * E_ + s2] = i;
    if (i < BN_) {
        const int b2 = i >> 12;
        const int s3 = atomicAdd(&gcur_n[b2 * G_ + ngi[i]], 1);
        gelist_n[b2 * N_ + s3] = i;
    }
}

// -------- edge GEMM: B whole-half async in LDS, A all-upfront in regs ------
// block: 128 rows x 64 cols, 4 waves x 32 rows; one barrier; K-loop pure LDS.
__global__ __launch_bounds__(256) void edge_mfma(
    const float* __restrict__ edges, const u16* __restrict__ nodesB,
    const u16* __restrict__ globB,
    const int* __restrict__ receivers, const int* __restrict__ senders,
    const int* __restrict__ egi,
    const u16* __restrict__ WeT2, const float* __restrict__ be,
    float* __restrict__ uE) {
    __shared__ u16 Bs[64 * 512];               // 64 KB pre-swizzled B image
    const int tid = threadIdx.x;
    const int bid = blockIdx.x;                // 2048
    const int bb = bid & 7;                    // batch = XCD
    const int jj = bid >> 3;                   // 0..255
    const int ch = jj & 1;
    const int rt = jj >> 1;                    // 0..127
    const int row0 = bb * E_ + rt * 128;

    const int wv = tid >> 6, l = tid & 63;
    const int fr = l & 15, fg = l >> 4;
    const int rowbase = row0 + wv * 32;
    const int R0 = rowbase + fr, R1 = R0 + 16;

    // ---- async B staging: 16 x 1KB per wave, linear dest (image pre-swz)
    {
        const char* wsrc = (const char*)(WeT2 + (long)ch * 32768) + l * 16;
        char* ldst = (char*)Bs;
        #pragma unroll
        for (int i2 = 0; i2 < 16; ++i2) {
            const int off = (wv * 16 + i2) * 1024;
            __builtin_amdgcn_global_load_lds(
                (const __attribute__((address_space(1))) void*)(wsrc + off),
                (__attribute__((address_space(3))) void*)(ldst + off),
                16, 0, 0);
        }
    }

    // ---- A gathers: ALL segments issued before the barrier
    const float* pE0 = edges + (long)R0 * DD;
    const float* pE1 = edges + (long)R1 * DD;
    const u16* nb = nodesB + (long)bb * (N_ * DD);
    const u16* aps0[3] = { nb + (long)senders[R0] * DD,
                           nb + (long)receivers[R0] * DD,
                           globB + ((long)bb * G_ + egi[R0]) * DD };
    const u16* aps1[3] = { nb + (long)senders[R1] * DD,
                           nb + (long)receivers[R1] * DD,
                           globB + ((long)bb * G_ + egi[R1]) * DD };
    short8 P0[3][4], P1[3][4];
    #pragma unroll
    for (int s = 0; s < 3; ++s) {
        #pragma unroll
        for (int ss = 0; ss < 4; ++ss) {
            P0[s][ss] = *(const short8*)(aps0[s] + ss * 32 + fg * 8);
            P1[s][ss] = *(const short8*)(aps1[s] + ss * 32 + fg * 8);
        }
    }
    short8 A0[4], A1[4];
    #pragma unroll
    for (int ss = 0; ss < 4; ++ss) {
        const int off = ss * 32 + fg * 8;
        A0[ss] = pack8(*(const float4*)(pE0 + off), *(const float4*)(pE0 + off + 4));
        A1[ss] = pack8(*(const float4*)(pE1 + off), *(const float4*)(pE1 + off + 4));
    }

    f32x4 acc0[4], acc1[4];
    const f32x4 fz = {0.f, 0.f, 0.f, 0.f};
    #pragma unroll
    for (int i = 0; i < 4; ++i) { acc0[i] = fz; acc1[i] = fz; }

    __syncthreads();   // vmcnt(0) drain: B in LDS, all A in regs

    // ---- K loop: pure ds_read_b128 + MFMA, no barriers, no global loads
    const char* bsp = (const char*)Bs;
    const int swr = (fr & 7) << 4;
    #pragma unroll
    for (int seg = 0; seg < 4; ++seg) {
        __builtin_amdgcn_s_setprio(1);
        #pragma unroll
        for (int ss = 0; ss < 4; ++ss) {
            short8 bfr[4];
            #pragma unroll
            for (int nt = 0; nt < 4; ++nt) {
                const int addr = (nt * 16 + fr) * 1024 +
                                 ((seg * 256 + ss * 64 + fg * 16) ^ swr);
                bfr[nt] = *(const short8*)(bsp + addr);
            }
            #pragma unroll
            for (int nt = 0; nt < 4; ++nt) {
                acc0[nt] = __builtin_amdgcn_mfma_f32_16x16x32_bf16(bfr[nt], A0[ss], acc0[nt], 0, 0, 0);
                acc1[nt] = __builtin_amdgcn_mfma_f32_16x16x32_bf16(bfr[nt], A1[ss], acc1[nt], 0, 0, 0);
            }
        }
        __builtin_amdgcn_s_setprio(0);
        if (seg < 3) {
            #pragma unroll
            for (int ss = 0; ss < 4; ++ss) { A0[ss] = P0[seg][ss]; A1[ss] = P1[seg][ss]; }
        }
    }

    // epilogue (swapped D): lane owns cols c..c+3 at rows R0/R1
    #pragma unroll
    for (int nt = 0; nt < 4; ++nt) {
        const int c = ch * 64 + nt * 16 + fg * 4;
        const float4 bv = *(const float4*)(be + c);
        float4 o0, o1;
        o0.x = fmaxf(acc0[nt][0] + bv.x, 0.f);
        o0.y = fmaxf(acc0[nt][1] + bv.y, 0.f);
        o0.z = fmaxf(acc0[nt][2] + bv.z, 0.f);
        o0.w = fmaxf(acc0[nt][3] + bv.w, 0.f);
        o1.x = fmaxf(acc1[nt][0] + bv.x, 0.f);
        o1.y = fmaxf(acc1[nt][1] + bv.y, 0.f);
        o1.z = fmaxf(acc1[nt][2] + bv.z, 0.f);
        o1.w = fmaxf(acc1[nt][3] + bv.w, 0.f);
        *(float4*)(uE + (long)R0 * DD + c) = o0;
        *(float4*)(uE + (long)R1 * DD + c) = o1;
    }
}

// -------- adj = CSR gather-sum of u_e rows, written as bf16 --------
__global__ __launch_bounds__(256) void adj_gather(
    const int* __restrict__ cur, const int* __restrict__ cnt,
    const int* __restrict__ elist, const float* __restrict__ uE,
    u16* __restrict__ adjB) {
    const int tid = threadIdx.x;
    const int row = blockIdx.x * 64 + (tid >> 2);
    const int q = tid & 3;
    const int bb = row >> 12;
    const int deg = cnt[row];
    const int start = cur[row] - deg;
    const int* lp = elist + (long)bb * E_ + start;
    float4 a[8];
    #pragma unroll
    for (int j = 0; j < 8; ++j) a[j] = {0.f, 0.f, 0.f, 0.f};
    for (int i = 0; i < deg; ++i) {
        const float* up = uE + (long)lp[i] * DD + q * 32;
        #pragma unroll
        for (int j = 0; j < 8; ++j) {
            const float4 v = *(const float4*)(up + j * 4);
            a[j].x += v.x; a[j].y += v.y; a[j].z += v.z; a[j].w += v.w;
        }
    }
    u16* dst = adjB + (long)row * DD + q * 32;
    #pragma unroll
    for (int j = 0; j < 4; ++j)
        *(short8*)(dst + j * 8) = pack8(a[2 * j], a[2 * j + 1]);
}

// -------- node GEMM: same one-barrier structure, K = 3 segs of 128 --------
__global__ __launch_bounds__(256) void node_mfma(
    const u16* __restrict__ nodesB, const u16* __restrict__ adjB,
    const u16* __restrict__ globB, const int* __restrict__ ngi,
    const u16* __restrict__ WnT2, const float* __restrict__ bn,
    float* __restrict__ uN) {
    __shared__ u16 Bs[64 * 384];               // 48 KB pre-swizzled B image
    const int tid = threadIdx.x;
    const int bid = blockIdx.x;                // 512
    const int bb = bid & 7;
    const int jj = bid >> 3;                   // 0..63
    const int ch = jj & 1;
    const int rt = jj >> 1;                    // 0..31
    const int row0 = bb * N_ + rt * 128;

    const int wv = tid >> 6, l = tid & 63;
    const int fr = l & 15, fg = l >> 4;
    const int rowbase = row0 + wv * 32;
    const int R0 = rowbase + fr, R1 = R0 + 16;

    {
        const char* wsrc = (const char*)(WnT2 + (long)ch * 24576) + l * 16;
        char* ldst = (char*)Bs;
        #pragma unroll
        for (int i2 = 0; i2 < 12; ++i2) {
            const int off = (wv * 12 + i2) * 1024;
            __builtin_amdgcn_global_load_lds(
                (const __attribute__((address_space(1))) void*)(wsrc + off),
                (__attribute__((address_space(3))) void*)(ldst + off),
                16, 0, 0);
        }
    }

    const u16* aps0[3] = { nodesB + (long)R0 * DD, adjB + (long)R0 * DD,
                           globB + ((long)bb * G_ + ngi[R0]) * DD };
    const u16* aps1[3] = { nodesB + (long)R1 * DD, adjB + (long)R1 * DD,
                           globB + ((long)bb * G_ + ngi[R1]) * DD };
    short8 P0[3][4], P1[3][4];
    #pragma unroll
    for (int s = 0; s < 3; ++s) {
        #pragma unroll
        for (int ss = 0; ss < 4; ++ss) {
            P0[s][ss] = *(const short8*)(aps0[s] + ss * 32 + fg * 8);
            P1[s][ss] = *(const short8*)(aps1[s] + ss * 32 + fg * 8);
        }
    }

    f32x4 acc0[4], acc1[4];
    const f32x4 fz = {0.f, 0.f, 0.f, 0.f};
    #pragma unroll
    for (int i = 0; i < 4; ++i) { acc0[i] = fz; acc1[i] = fz; }

    __syncthreads();

    const char* bsp = (const char*)Bs;
    const int swr = (fr & 7) << 4;
    #pragma unroll
    for (int seg = 0; seg < 3; ++seg) {
        __builtin_amdgcn_s_setprio(1);
        #pragma unroll
        for (int ss = 0; ss < 4; ++ss) {
            short8 bfr[4];
            #pragma unroll
            for (int nt = 0; nt < 4; ++nt) {
                const int addr = (nt * 16 + fr) * 768 +
                                 ((seg * 256 + ss * 64 + fg * 16) ^ swr);
                bfr[nt] = *(const short8*)(bsp + addr);
            }
            #pragma unroll
            for (int nt = 0; nt < 4; ++nt) {
                acc0[nt] = __builtin_amdgcn_mfma_f32_16x16x32_bf16(bfr[nt], P0[seg][ss], acc0[nt], 0, 0, 0);
                acc1[nt] = __builtin_amdgcn_mfma_f32_16x16x32_bf16(bfr[nt], P1[seg][ss], acc1[nt], 0, 0, 0);
            }
        }
        __builtin_amdgcn_s_setprio(0);
    }

    #pragma unroll
    for (int nt = 0; nt < 4; ++nt) {
        const int c = ch * 64 + nt * 16 + fg * 4;
        const float4 bv = *(const float4*)(bn + c);
        float4 o0, o1;
        o0.x = fmaxf(acc0[nt][0] + bv.x, 0.f);
        o0.y = fmaxf(acc0[nt][1] + bv.y, 0.f);
        o0.z = fmaxf(acc0[nt][2] + bv.z, 0.f);
        o0.w = fmaxf(acc0[nt][3] + bv.w, 0.f);
        o1.x = fmaxf(acc1[nt][0] + bv.x, 0.f);
        o1.y = fmaxf(acc1[nt][1] + bv.y, 0.f);
        o1.z = fmaxf(acc1[nt][2] + bv.z, 0.f);
        o1.w = fmaxf(acc1[nt][3] + bv.w, 0.f);
        *(float4*)(uN + (long)R0 * DD + c) = o0;
        *(float4*)(uN + (long)R1 * DD + c) = o1;
    }
}

// -------- aggregate + fused residual, PART-way split --------
__global__ __launch_bounds__(256) void agg_resid(
    const int* __restrict__ gcnt, const int* __restrict__ gcur,
    const int* __restrict__ gelist, int spb,
    const float* __restrict__ xin, const float* __restrict__ w_res,
    float* __restrict__ u /* in-place -> x_out */,
    float* __restrict__ aggp /* [PART][BG][DD] */) {
    __shared__ float accl[1024];
    const int bg = blockIdx.x >> 3;            // grid = BG*PART
    const int p  = blockIdx.x & 7;
    const int b = bg >> 6;
    const int tid = threadIdx.x;
    const int c4 = (tid & 31) << 2;
    const int sub = tid >> 5;                  // 0..7
    const int m = gcnt[bg];
    const int* lp = gelist + (long)b * spb + (gcur[bg] - m);
    const float wr = w_res[0];
    f32x4 acc = {0.f, 0.f, 0.f, 0.f};
    for (int j = p * 8 + sub; j < m; j += 64) {
        const long re = (long)lp[j] * DD + c4;
        const float4 v = *(const float4*)(u + re);
        const float4 x = *(const float4*)(xin + re);
        acc[0] += v.x; acc[1] += v.y; acc[2] += v.z; acc[3] += v.w;
        float4 o;
        o.x = x.x + wr * v.x; o.y = x.y + wr * v.y;
        o.z = x.z + wr * v.z; o.w = x.w + wr * v.w;
        *(float4*)(u + re) = o;
    }
    *(f32x4*)&accl[sub * 128 + c4] = acc;
    __syncthreads();
    if (tid < 128) {
        float s = 0.f;
        #pragma unroll
        for (int q = 0; q < 8; ++q) s += accl[q * 128 + tid];
        aggp[((long)p * BG_ + bg) * DD + tid] = s;
    }
}

// ---------------- global block: 512 rows, K=384, fp32 VALU ----------------
__global__ __launch_bounds__(128) void global_block(
    const float* __restrict__ naggp, const float* __restrict__ eaggp,
    const float* __restrict__ glob,
    const float* __restrict__ Wg, const float* __restrict__ bgb,
    const float* __restrict__ w_res, float* __restrict__ out) {
    __shared__ float gin[384];
    const int row = blockIdx.x;
    const int tid = threadIdx.x;
    float sn = 0.f, se = 0.f;
    #pragma unroll
    for (int p = 0; p < PART; ++p) {
        sn += naggp[((long)p * BG_ + row) * DD + tid];
        se += eaggp[((long)p * BG_ + row) * DD + tid];
    }
    gin[tid]       = sn;
    gin[128 + tid] = se;
    gin[256 + tid] = glob[row * DD + tid];
    __syncthreads();
    float acc = bgb[tid];
    #pragma unroll 4
    for (int k = 0; k < 384; ++k) acc += gin[k] * Wg[k * DD + tid];
    const float upd = fmaxf(acc, 0.f);
    out[OFF_GLOB + row * DD + tid] = glob[row * DD + tid] + w_res[0] * upd;
}

extern "C" void kernel_launch(void* const* d_in, const int* in_sizes, int n_in,
                              void* d_out, int out_size, void* d_ws, size_t ws_size,
                              hipStream_t stream) {
    const float* nodes     = (const float*)d_in[0];
    const float* edges     = (const float*)d_in[1];
    const int*   receivers = (const int*)d_in[2];
    const int*   senders   = (const int*)d_in[3];
    const float* glob      = (const float*)d_in[4];
    const int*   ngi       = (const int*)d_in[5];
    const int*   egi       = (const int*)d_in[6];
    const float* We        = (const float*)d_in[7];
    const float* be        = (const float*)d_in[8];
    const float* Wn        = (const float*)d_in[9];
    const float* bn        = (const float*)d_in[10];
    const float* Wg        = (const float*)d_in[11];
    const float* bg        = (const float*)d_in[12];
    const float* w_res     = (const float*)d_in[13];
    float* out = (float*)d_out;
    float* ws  = (float*)d_ws;

    float* eaggp = ws + WS_EAGGP;
    float* naggp = ws + WS_NAGGP;
    int* cnt      = (int*)(ws + WS_CNT);
    int* gcnt_e   = (int*)(ws + WS_GCNTE);
    int* gcnt_n   = (int*)(ws + WS_GCNTN);
    int* cur      = (int*)(ws + WS_CUR);
    int* gcur_e   = (int*)(ws + WS_GCURE);
    int* gcur_n   = (int*)(ws + WS_GCURN);
    int* elist    = (int*)(ws + WS_ELIST);
    int* gelist_e = (int*)(ws + WS_GELE);
    int* gelist_n = (int*)(ws + WS_GELN);
    u16* adjB   = (u16*)(ws + WS_ADJB);
    u16* nodesB = (u16*)(ws + WS_NODB);
    u16* globB  = (u16*)(ws + WS_GLOBB);
    u16* WeT2   = (u16*)(ws + WS_WET);
    u16* WnT2   = (u16*)(ws + WS_WNT);

    float* uE = out + OFF_EDGES;   // u_e, becomes edges_out after agg_resid
    float* uN = out + OFF_NODES;   // u_n, becomes nodes_out after agg_resid

    hipLaunchKernelGGL(prep_w, dim3(448), dim3(256), 0, stream, We, Wn, WeT2, WnT2);
    hipLaunchKernelGGL(cast_bf16, dim3(2080), dim3(256), 0, stream,
                       nodes, glob, nodesB, globB);
    hipLaunchKernelGGL(init_misc, dim3(1796), dim3(256), 0, stream,
                       receivers, senders, ngi, egi, out, cnt);
    hipLaunchKernelGGL(k_hist_all, dim3(512), dim3(256), 0, stream,
                       receivers, egi, ngi, cnt, gcnt_e, gcnt_n);
    hipLaunchKernelGGL(k_scan, dim3(8), dim3(1024), 0, stream,
                       cnt, cur, gcnt_e, gcur_e, gcnt_n, gcur_n);
    hipLaunchKernelGGL(k_fill_all, dim3(512), dim3(256), 0, stream,
                       receivers, egi, ngi, cur, elist, gcur_e, gelist_e,
                       gcur_n, gelist_n);
    hipLaunchKernelGGL(edge_mfma, dim3(2048), dim3(256), 0, stream,
                       edges, nodesB, globB, receivers, senders, egi, WeT2, be, uE);
    hipLaunchKernelGGL(adj_gather, dim3(BN_ / 64), dim3(256), 0, stream,
                       cur, cnt, elist, uE, adjB);
    hipLaunchKernelGGL(agg_resid, dim3(BG_ * PART), dim3(256), 0, stream,
                       gcnt_e, gcur_e, gelist_e, E_, edges, w_res, uE, eaggp);
    hipLaunchKernelGGL(node_mfma, dim3(512), dim3(256), 0, stream,
                       nodesB, adjB, globB, ngi, WnT2, bn, uN);
    hipLaunchKernelGGL(agg_resid, dim3(BG_ * PART), dim3(256), 0, stream,
                       gcnt_n, gcur_n, gelist_n, N_, nodes, w_res, uN, naggp);
    hipLaunchKernelGGL(global_block, dim3(BG_), dim3(128), 0, stream,
                       naggp, eaggp, glob, Wg, bg, w_res, out);
}

// Round 10
// 233.209 us; speedup vs baseline: 1.0840x; 1.0840x over previous
//
#include <hip/hip_runtime.h>

// GraphNetworkLayer: B=8, N=4096, E=16384, G=64, D=128, fp32 in/out.
// Round 10:
//  - edge/node MFMA: asm-volatile KEEP-ALIVE fences pin all prefetched A
//    fragments in registers BEFORE the barrier (defeats compiler load-sinking
//    that nullified R6/R8/R9 prefetch). B stays whole-half async LDS (R9).
//  - edge epilogue fuses the residual: writes edges_out = edges + wr*u to
//    d_out directly (edges rows L2-warm from staging) AND u as bf16 to uEb.
//  - adj_gather + agg_only(e) read bf16 u: post-edge traffic 268MB -> ~100MB.
//  - node path keeps fp32 u + agg_resid(n) (small). PART=4.
// No float atomics anywhere.

#define DD 128
typedef unsigned short u16;
typedef __attribute__((ext_vector_type(8))) short short8;   // 8 bf16
typedef __attribute__((ext_vector_type(4))) short s16x4;    // 4 bf16
typedef __attribute__((ext_vector_type(4))) float f32x4;

constexpr int B_ = 8, N_ = 4096, E_ = 16384, G_ = 64;
constexpr int NODES_SZ = B_ * N_ * DD;   // 4,194,304
constexpr int EDGES_SZ = B_ * E_ * DD;   // 16,777,216
constexpr int BE_ = B_ * E_;             // 131,072
constexpr int BN_ = B_ * N_;             // 32,768
constexpr int BG_ = B_ * G_;             // 512
constexpr int GLOB_SZ = BG_ * DD;        // 65,536
constexpr int PART = 4;

constexpr int OFF_NODES = 0;
constexpr int OFF_EDGES = OFF_NODES + NODES_SZ;
constexpr int OFF_RECV  = OFF_EDGES + EDGES_SZ;
constexpr int OFF_SEND  = OFF_RECV + BE_;
constexpr int OFF_GLOB  = OFF_SEND + BE_;
constexpr int OFF_NGI   = OFF_GLOB + GLOB_SZ;
constexpr int OFF_EGI   = OFF_NGI + BN_;

// ws layout (float-element offsets) — total ~13.56M floats = 54.2 MB
constexpr int WS_EAGGP = 0;                          // [PART][BG][DD] f32
constexpr int WS_NAGGP = WS_EAGGP + PART * GLOB_SZ;
constexpr int WS_CNT   = WS_NAGGP + PART * GLOB_SZ;  // int [B*N] (zeroed)
constexpr int WS_GCNTE = WS_CNT + BN_;               // int [512] (zeroed)
constexpr int WS_GCNTN = WS_GCNTE + 512;             // int [512] (zeroed)
constexpr int WS_CUR   = WS_GCNTN + 512;             // int [B*N]
constexpr int WS_GCURE = WS_CUR + BN_;               // int [512]
constexpr int WS_GCURN = WS_GCURE + 512;             // int [512]
constexpr int WS_ELIST = WS_GCURN + 512;             // int [B*E]
constexpr int WS_GELE  = WS_ELIST + BE_;             // int [B*E]
constexpr int WS_GELN  = WS_GELE + BE_;              // int [B*N]
constexpr int WS_ADJB  = WS_GELN + BN_;              // u16 [B,N,D]
constexpr int WS_NODB  = WS_ADJB + (BN_ * DD) / 2;   // u16 [B,N,D]
constexpr int WS_GLOBB = WS_NODB + (BN_ * DD) / 2;   // u16 [B,G,D]
constexpr int WS_WET   = WS_GLOBB + GLOB_SZ / 2;     // u16 [128*512] swz image
constexpr int WS_WNT   = WS_WET + 32768;             // u16 [128*384] swz image
constexpr int WS_UEB   = WS_WNT + 24576;             // u16 [B,E,D] bf16 u_e

__device__ inline u16 f2bf(float f) {
    union { float f; unsigned u; } v; v.f = f;
    return (u16)((v.u + 0x7fffu + ((v.u >> 16) & 1u)) >> 16);
}
__device__ inline float bf2f(u16 h) {
    union { unsigned u; float f; } v; v.u = ((unsigned)h) << 16; return v.f;
}
__device__ inline short8 pack8(float4 a, float4 b) {
    short8 r;
    r[0] = (short)f2bf(a.x); r[1] = (short)f2bf(a.y);
    r[2] = (short)f2bf(a.z); r[3] = (short)f2bf(a.w);
    r[4] = (short)f2bf(b.x); r[5] = (short)f2bf(b.y);
    r[6] = (short)f2bf(b.z); r[7] = (short)f2bf(b.w);
    return r;
}

#define KEEP4(a0, a1, a2, a3) \
    asm volatile("" :: "v"(a0), "v"(a1), "v"(a2), "v"(a3))

__global__ __launch_bounds__(256) void prep_w(
    const float* __restrict__ We, const float* __restrict__ Wn,
    u16* __restrict__ WeT2, u16* __restrict__ WnT2) {
    const int i = blockIdx.x * blockDim.x + threadIdx.x;
    if (i < 65536) {
        const int ch = i >> 15;
        const int r = i & 32767;
        const int row = r >> 9;
        const int inb = (r << 1) & 1023;
        const int kb = inb ^ ((row & 7) << 4);
        WeT2[i] = f2bf(We[(kb >> 1) * DD + ch * 64 + row]);
    } else {
        const int q = i - 65536;
        if (q < 49152) {
            const int ch = q / 24576;
            const int r = q % 24576;
            const int row = r / 384;
            const int inb = (r % 384) << 1;
            const int kb = inb ^ ((row & 7) << 4);
            WnT2[q] = f2bf(Wn[(kb >> 1) * DD + ch * 64 + row]);
        }
    }
}

__global__ __launch_bounds__(256) void cast_bf16(
    const float* __restrict__ nodes, const float* __restrict__ glob,
    u16* __restrict__ nodesB, u16* __restrict__ globB) {
    const int i = blockIdx.x * 256 + threadIdx.x;
    const int NT = NODES_SZ / 8;
    if (i < NT) {
        const float4 a = *(const float4*)(nodes + (long)i * 8);
        const float4 b = *(const float4*)(nodes + (long)i * 8 + 4);
        *(short8*)(nodesB + (long)i * 8) = pack8(a, b);
    } else {
        const int j = i - NT;
        const float4 a = *(const float4*)(glob + (long)j * 8);
        const float4 b = *(const float4*)(glob + (long)j * 8 + 4);
        *(short8*)(globB + (long)j * 8) = pack8(a, b);
    }
}

__global__ __launch_bounds__(256) void init_misc(
    const int* __restrict__ recv, const int* __restrict__ send,
    const int* __restrict__ ngi, const int* __restrict__ egi,
    float* __restrict__ out, int* __restrict__ zbase) {
    const int i = blockIdx.x * 256 + threadIdx.x;
    const int total = 3 * BE_ + BN_;
    if (i < total) {
        if (i < BE_)                 out[OFF_RECV + i] = (float)recv[i];
        else if (i < 2 * BE_)        out[OFF_SEND + (i - BE_)] = (float)send[i - BE_];
        else if (i < 2 * BE_ + BN_)  out[OFF_NGI + (i - 2 * BE_)] = (float)ngi[i - 2 * BE_];
        else                         out[OFF_EGI + (i - 2 * BE_ - BN_)] = (float)egi[i - 2 * BE_ - BN_];
    } else {
        const int j = i - total;
        if (j < BN_ + 1024) zbase[j] = 0;
    }
}

__global__ __launch_bounds__(256) void k_hist_all(
    const int* __restrict__ recv, const int* __restrict__ egi,
    const int* __restrict__ ngi,
    int* __restrict__ cnt, int* __restrict__ gcnt_e, int* __restrict__ gcnt_n) {
    const int i = blockIdx.x * 256 + threadIdx.x;
    const int b = i >> 14;
    atomicAdd(&cnt[b * N_ + recv[i]], 1);
    atomicAdd(&gcnt_e[b * G_ + egi[i]], 1);
    if (i < BN_) atomicAdd(&gcnt_n[(i >> 12) * G_ + ngi[i]], 1);
}

__global__ __launch_bounds__(1024) void k_scan(
    const int* __restrict__ cnt, int* __restrict__ cur,
    const int* __restrict__ gcnt_e, int* __restrict__ gcur_e,
    const int* __restrict__ gcnt_n, int* __restrict__ gcur_n) {
    __shared__ int s[1024];
    const int b = blockIdx.x;
    const int t = threadIdx.x;
    const int base = b * N_;
    int c[4];
    int sum = 0;
    #pragma unroll
    for (int i = 0; i < 4; ++i) { c[i] = cnt[base + 4 * t + i]; sum += c[i]; }
    s[t] = sum;
    __syncthreads();
    for (int off = 1; off < 1024; off <<= 1) {
        int v = s[t];
        if (t >= off) v += s[t - off];
        __syncthreads();
        s[t] = v;
        __syncthreads();
    }
    int eb = s[t] - sum;
    #pragma unroll
    for (int i = 0; i < 4; ++i) { cur[base + 4 * t + i] = eb; eb += c[i]; }
    __syncthreads();
    int gv = 0;
    if (t < G_) { gv = gcnt_e[b * G_ + t]; s[t] = gv; }
    __syncthreads();
    for (int off = 1; off < G_; off <<= 1) {
        int v = 0;
        if (t < G_) { v = s[t]; if (t >= off) v += s[t - off]; }
        __syncthreads();
        if (t < G_) s[t] = v;
        __syncthreads();
    }
    if (t < G_) gcur_e[b * G_ + t] = s[t] - gv;
    __syncthreads();
    if (t < G_) { gv = gcnt_n[b * G_ + t]; s[t] = gv; }
    __syncthreads();
    for (int off = 1; off < G_; off <<= 1) {
        int v = 0;
        if (t < G_) { v = s[t]; if (t >= off) v += s[t - off]; }
        __syncthreads();
        if (t < G_) s[t] = v;
        __syncthreads();
    }
    if (t < G_) gcur_n[b * G_ + t] = s[t] - gv;
}

__global__ __launch_bounds__(256) void k_fill_all(
    const int* __restrict__ recv, const int* __restrict__ egi,
    const int* __restrict__ ngi,
    int* __restrict__ cur, int* __restrict__ elist,
    int* __restrict__ gcur_e, int* __restrict__ gelist_e,
    int* __restrict__ gcur_n, int* __restrict__ gelist_n) {
    const int i = blockIdx.x * 256 + threadIdx.x;
    const int b = i >> 14;
    const int s1 = atomicAdd(&cur[b * N_ + recv[i]], 1);
    elist[b * E_ + s1] = i;
    const int s2 = atomicAdd(&gcur_e[b * G_ + egi[i]], 1);
    gelist_e[b * E_ + s2] = i;
    if (i < BN_) {
        const int b2 = i >> 12;
        const int s3 = atomicAdd(&gcur_n[b2 * G_ + ngi[i]], 1);
        gelist_n[b2 * N_ + s3] = i;
    }
}

// -------- edge GEMM: B async-LDS, A reg-resident (keep-alive pinned),
// fused residual epilogue: edges_out fp32 -> out, u bf16 -> uEb.
__global__ __launch_bounds__(256) void edge_mfma(
    const float* __restrict__ edges, const u16* __restrict__ nodesB,
    const u16* __restrict__ globB,
    const int* __restrict__ receivers, const int* __restrict__ senders,
    const int* __restrict__ egi,
    const u16* __restrict__ WeT2, const float* __restrict__ be,
    const float* __restrict__ w_res,
    float* __restrict__ outE, u16* __restrict__ uEb) {
    __shared__ u16 Bs[64 * 512];               // 64 KB pre-swizzled B image
    const int tid = threadIdx.x;
    const int bid = blockIdx.x;                // 2048
    const int bb = bid & 7;                    // batch = XCD
    const int jj = bid >> 3;                   // 0..255
    const int ch = jj & 1;
    const int rt = jj >> 1;                    // 0..127
    const int row0 = bb * E_ + rt * 128;

    const int wv = tid >> 6, l = tid & 63;
    const int fr = l & 15, fg = l >> 4;
    const int rowbase = row0 + wv * 32;
    const int R0 = rowbase + fr, R1 = R0 + 16;

    // async B staging: 16 x 1KB per wave, linear dest (image pre-swizzled)
    {
        const char* wsrc = (const char*)(WeT2 + (long)ch * 32768) + l * 16;
        char* ldst = (char*)Bs;
        #pragma unroll
        for (int i2 = 0; i2 < 16; ++i2) {
            const int off = (wv * 16 + i2) * 1024;
            __builtin_amdgcn_global_load_lds(
                (const __attribute__((address_space(1))) void*)(wsrc + off),
                (__attribute__((address_space(3))) void*)(ldst + off),
                16, 0, 0);
        }
    }

    // A gathers: ALL segments, pinned in regs by keep-alive before barrier
    const float* pE0 = edges + (long)R0 * DD;
    const float* pE1 = edges + (long)R1 * DD;
    const u16* nb = nodesB + (long)bb * (N_ * DD);
    const u16* aps0[3] = { nb + (long)senders[R0] * DD,
                           nb + (long)receivers[R0] * DD,
                           globB + ((long)bb * G_ + egi[R0]) * DD };
    const u16* aps1[3] = { nb + (long)senders[R1] * DD,
                           nb + (long)receivers[R1] * DD,
                           globB + ((long)bb * G_ + egi[R1]) * DD };
    short8 P0[3][4], P1[3][4];
    #pragma unroll
    for (int s = 0; s < 3; ++s) {
        #pragma unroll
        for (int ss = 0; ss < 4; ++ss) {
            P0[s][ss] = *(const short8*)(aps0[s] + ss * 32 + fg * 8);
            P1[s][ss] = *(const short8*)(aps1[s] + ss * 32 + fg * 8);
        }
    }
    short8 A0[4], A1[4];
    #pragma unroll
    for (int ss = 0; ss < 4; ++ss) {
        const int off = ss * 32 + fg * 8;
        A0[ss] = pack8(*(const float4*)(pE0 + off), *(const float4*)(pE0 + off + 4));
        A1[ss] = pack8(*(const float4*)(pE1 + off), *(const float4*)(pE1 + off + 4));
    }

    // pin everything in registers BEFORE the barrier (rule #17)
    KEEP4(P0[0][0], P0[0][1], P0[0][2], P0[0][3]);
    KEEP4(P0[1][0], P0[1][1], P0[1][2], P0[1][3]);
    KEEP4(P0[2][0], P0[2][1], P0[2][2], P0[2][3]);
    KEEP4(P1[0][0], P1[0][1], P1[0][2], P1[0][3]);
    KEEP4(P1[1][0], P1[1][1], P1[1][2], P1[1][3]);
    KEEP4(P1[2][0], P1[2][1], P1[2][2], P1[2][3]);
    KEEP4(A0[0], A0[1], A0[2], A0[3]);
    KEEP4(A1[0], A1[1], A1[2], A1[3]);

    f32x4 acc0[4], acc1[4];
    const f32x4 fz = {0.f, 0.f, 0.f, 0.f};
    #pragma unroll
    for (int i = 0; i < 4; ++i) { acc0[i] = fz; acc1[i] = fz; }

    __syncthreads();   // vmcnt(0) drain: B in LDS, all A in regs

    // K loop: pure ds_read_b128 + MFMA
    const char* bsp = (const char*)Bs;
    const int swr = (fr & 7) << 4;
    #pragma unroll
    for (int seg = 0; seg < 4; ++seg) {
        __builtin_amdgcn_s_setprio(1);
        #pragma unroll
        for (int ss = 0; ss < 4; ++ss) {
            short8 bfr[4];
            #pragma unroll
            for (int nt = 0; nt < 4; ++nt) {
                const int addr = (nt * 16 + fr) * 1024 +
                                 ((seg * 256 + ss * 64 + fg * 16) ^ swr);
                bfr[nt] = *(const short8*)(bsp + addr);
            }
            #pragma unroll
            for (int nt = 0; nt < 4; ++nt) {
                acc0[nt] = __builtin_amdgcn_mfma_f32_16x16x32_bf16(bfr[nt], A0[ss], acc0[nt], 0, 0, 0);
                acc1[nt] = __builtin_amdgcn_mfma_f32_16x16x32_bf16(bfr[nt], A1[ss], acc1[nt], 0, 0, 0);
            }
        }
        __builtin_amdgcn_s_setprio(0);
        if (seg < 3) {
            #pragma unroll
            for (int ss = 0; ss < 4; ++ss) { A0[ss] = P0[seg][ss]; A1[ss] = P1[seg][ss]; }
        }
    }

    // fused-residual epilogue: lane owns cols c..c+3 at rows R0/R1
    const float wr = w_res[0];
    #pragma unroll
    for (int nt = 0; nt < 4; ++nt) {
        const int c = ch * 64 + nt * 16 + fg * 4;
        const float4 bv = *(const float4*)(be + c);
        const float4 e0 = *(const float4*)(edges + (long)R0 * DD + c);
        const float4 e1 = *(const float4*)(edges + (long)R1 * DD + c);
        const float u00 = fmaxf(acc0[nt][0] + bv.x, 0.f);
        const float u01 = fmaxf(acc0[nt][1] + bv.y, 0.f);
        const float u02 = fmaxf(acc0[nt][2] + bv.z, 0.f);
        const float u03 = fmaxf(acc0[nt][3] + bv.w, 0.f);
        const float u10 = fmaxf(acc1[nt][0] + bv.x, 0.f);
        const float u11 = fmaxf(acc1[nt][1] + bv.y, 0.f);
        const float u12 = fmaxf(acc1[nt][2] + bv.z, 0.f);
        const float u13 = fmaxf(acc1[nt][3] + bv.w, 0.f);
        s16x4 h0, h1;
        h0[0] = (short)f2bf(u00); h0[1] = (short)f2bf(u01);
        h0[2] = (short)f2bf(u02); h0[3] = (short)f2bf(u03);
        h1[0] = (short)f2bf(u10); h1[1] = (short)f2bf(u11);
        h1[2] = (short)f2bf(u12); h1[3] = (short)f2bf(u13);
        *(s16x4*)(uEb + (long)R0 * DD + c) = h0;
        *(s16x4*)(uEb + (long)R1 * DD + c) = h1;
        float4 o0, o1;
        o0.x = e0.x + wr * u00; o0.y = e0.y + wr * u01;
        o0.z = e0.z + wr * u02; o0.w = e0.w + wr * u03;
        o1.x = e1.x + wr * u10; o1.y = e1.y + wr * u11;
        o1.z = e1.z + wr * u12; o1.w = e1.w + wr * u13;
        *(float4*)(outE + (long)R0 * DD + c) = o0;
        *(float4*)(outE + (long)R1 * DD + c) = o1;
    }
}

// -------- adj = CSR gather-sum of bf16 u_e rows -> bf16 adjB --------
__global__ __launch_bounds__(256) void adj_gather(
    const int* __restrict__ cur, const int* __restrict__ cnt,
    const int* __restrict__ elist, const u16* __restrict__ uEb,
    u16* __restrict__ adjB) {
    const int tid = threadIdx.x;
    const int row = blockIdx.x * 64 + (tid >> 2);
    const int q = tid & 3;
    const int bb = row >> 12;
    const int deg = cnt[row];
    const int start = cur[row] - deg;
    const int* lp = elist + (long)bb * E_ + start;
    float a[32];
    #pragma unroll
    for (int j = 0; j < 32; ++j) a[j] = 0.f;
    for (int i = 0; i < deg; ++i) {
        const u16* up = uEb + (long)lp[i] * DD + q * 32;
        #pragma unroll
        for (int j = 0; j < 4; ++j) {
            const short8 v = *(const short8*)(up + j * 8);
            #pragma unroll
            for (int e2 = 0; e2 < 8; ++e2) a[j * 8 + e2] += bf2f((u16)v[e2]);
        }
    }
    u16* dst = adjB + (long)row * DD + q * 32;
    #pragma unroll
    for (int j = 0; j < 4; ++j) {
        short8 h;
        #pragma unroll
        for (int e2 = 0; e2 < 8; ++e2) h[e2] = (short)f2bf(a[j * 8 + e2]);
        *(short8*)(dst + j * 8) = h;
    }
}

// -------- eagg = per-(b,g) gather-sum of bf16 u_e rows (no residual) ------
__global__ __launch_bounds__(256) void agg_only(
    const int* __restrict__ gcnt, const int* __restrict__ gcur,
    const int* __restrict__ gelist, const u16* __restrict__ uEb,
    float* __restrict__ aggp /* [PART][BG][DD] */) {
    __shared__ float accl[1024];
    const int bg = blockIdx.x >> 2;            // grid = BG*PART
    const int p  = blockIdx.x & 3;
    const int b = bg >> 6;
    const int tid = threadIdx.x;
    const int c4 = (tid & 31) << 2;
    const int sub = tid >> 5;                  // 0..7
    const int m = gcnt[bg];
    const int* lp = gelist + (long)b * E_ + (gcur[bg] - m);
    f32x4 acc = {0.f, 0.f, 0.f, 0.f};
    for (int j = p * 8 + sub; j < m; j += 32) {
        const u16* up = uEb + (long)lp[j] * DD + c4;
        const s16x4 v = *(const s16x4*)up;
        acc[0] += bf2f((u16)v[0]); acc[1] += bf2f((u16)v[1]);
        acc[2] += bf2f((u16)v[2]); acc[3] += bf2f((u16)v[3]);
    }
    *(f32x4*)&accl[sub * 128 + c4] = acc;
    __syncthreads();
    if (tid < 128) {
        float s = 0.f;
        #pragma unroll
        for (int q = 0; q < 8; ++q) s += accl[q * 128 + tid];
        aggp[((long)p * BG_ + bg) * DD + tid] = s;
    }
}

// -------- node GEMM: keep-alive pinned A, K = 3 segs of 128 --------
__global__ __launch_bounds__(256) void node_mfma(
    const u16* __restrict__ nodesB, const u16* __restrict__ adjB,
    const u16* __restrict__ globB, const int* __restrict__ ngi,
    const u16* __restrict__ WnT2, const float* __restrict__ bn,
    float* __restrict__ uN) {
    __shared__ u16 Bs[64 * 384];               // 48 KB pre-swizzled B image
    const int tid = threadIdx.x;
    const int bid = blockIdx.x;                // 512
    const int bb = bid & 7;
    const int jj = bid >> 3;                   // 0..63
    const int ch = jj & 1;
    const int rt = jj >> 1;                    // 0..31
    const int row0 = bb * N_ + rt * 128;

    const int wv = tid >> 6, l = tid & 63;
    const int fr = l & 15, fg = l >> 4;
    const int rowbase = row0 + wv * 32;
    const int R0 = rowbase + fr, R1 = R0 + 16;

    {
        const char* wsrc = (const char*)(WnT2 + (long)ch * 24576) + l * 16;
        char* ldst = (char*)Bs;
        #pragma unroll
        for (int i2 = 0; i2 < 12; ++i2) {
            const int off = (wv * 12 + i2) * 1024;
            __builtin_amdgcn_global_load_lds(
                (const __attribute__((address_space(1))) void*)(wsrc + off),
                (__attribute__((address_space(3))) void*)(ldst + off),
                16, 0, 0);
        }
    }

    const u16* aps0[3] = { nodesB + (long)R0 * DD, adjB + (long)R0 * DD,
                           globB + ((long)bb * G_ + ngi[R0]) * DD };
    const u16* aps1[3] = { nodesB + (long)R1 * DD, adjB + (long)R1 * DD,
                           globB + ((long)bb * G_ + ngi[R1]) * DD };
    short8 P0[3][4], P1[3][4];
    #pragma unroll
    for (int s = 0; s < 3; ++s) {
        #pragma unroll
        for (int ss = 0; ss < 4; ++ss) {
            P0[s][ss] = *(const short8*)(aps0[s] + ss * 32 + fg * 8);
            P1[s][ss] = *(const short8*)(aps1[s] + ss * 32 + fg * 8);
        }
    }
    KEEP4(P0[0][0], P0[0][1], P0[0][2], P0[0][3]);
    KEEP4(P0[1][0], P0[1][1], P0[1][2], P0[1][3]);
    KEEP4(P0[2][0], P0[2][1], P0[2][2], P0[2][3]);
    KEEP4(P1[0][0], P1[0][1], P1[0][2], P1[0][3]);
    KEEP4(P1[1][0], P1[1][1], P1[1][2], P1[1][3]);
    KEEP4(P1[2][0], P1[2][1], P1[2][2], P1[2][3]);

    f32x4 acc0[4], acc1[4];
    const f32x4 fz = {0.f, 0.f, 0.f, 0.f};
    #pragma unroll
    for (int i = 0; i < 4; ++i) { acc0[i] = fz; acc1[i] = fz; }

    __syncthreads();

    const char* bsp = (const char*)Bs;
    const int swr = (fr & 7) << 4;
    #pragma unroll
    for (int seg = 0; seg < 3; ++seg) {
        __builtin_amdgcn_s_setprio(1);
        #pragma unroll
        for (int ss = 0; ss < 4; ++ss) {
            short8 bfr[4];
            #pragma unroll
            for (int nt = 0; nt < 4; ++nt) {
                const int addr = (nt * 16 + fr) * 768 +
                                 ((seg * 256 + ss * 64 + fg * 16) ^ swr);
                bfr[nt] = *(const short8*)(bsp + addr);
            }
            #pragma unroll
            for (int nt = 0; nt < 4; ++nt) {
                acc0[nt] = __builtin_amdgcn_mfma_f32_16x16x32_bf16(bfr[nt], P0[seg][ss], acc0[nt], 0, 0, 0);
                acc1[nt] = __builtin_amdgcn_mfma_f32_16x16x32_bf16(bfr[nt], P1[seg][ss], acc1[nt], 0, 0, 0);
            }
        }
        __builtin_amdgcn_s_setprio(0);
    }

    #pragma unroll
    for (int nt = 0; nt < 4; ++nt) {
        const int c = ch * 64 + nt * 16 + fg * 4;
        const float4 bv = *(const float4*)(bn + c);
        float4 o0, o1;
        o0.x = fmaxf(acc0[nt][0] + bv.x, 0.f);
        o0.y = fmaxf(acc0[nt][1] + bv.y, 0.f);
        o0.z = fmaxf(acc0[nt][2] + bv.z, 0.f);
        o0.w = fmaxf(acc0[nt][3] + bv.w, 0.f);
        o1.x = fmaxf(acc1[nt][0] + bv.x, 0.f);
        o1.y = fmaxf(acc1[nt][1] + bv.y, 0.f);
        o1.z = fmaxf(acc1[nt][2] + bv.z, 0.f);
        o1.w = fmaxf(acc1[nt][3] + bv.w, 0.f);
        *(float4*)(uN + (long)R0 * DD + c) = o0;
        *(float4*)(uN + (long)R1 * DD + c) = o1;
    }
}

// -------- node aggregate + fused residual (fp32 u in d_out) --------
__global__ __launch_bounds__(256) void agg_resid(
    const int* __restrict__ gcnt, const int* __restrict__ gcur,
    const int* __restrict__ gelist, int spb,
    const float* __restrict__ xin, const float* __restrict__ w_res,
    float* __restrict__ u /* in-place -> x_out */,
    float* __restrict__ aggp /* [PART][BG][DD] */) {
    __shared__ float accl[1024];
    const int bg = blockIdx.x >> 2;            // grid = BG*PART
    const int p  = blockIdx.x & 3;
    const int b = bg >> 6;
    const int tid = threadIdx.x;
    const int c4 = (tid & 31) << 2;
    const int sub = tid >> 5;                  // 0..7
    const int m = gcnt[bg];
    const int* lp = gelist + (long)b * spb + (gcur[bg] - m);
    const float wr = w_res[0];
    f32x4 acc = {0.f, 0.f, 0.f, 0.f};
    for (int j = p * 8 + sub; j < m; j += 32) {
        const long re = (long)lp[j] * DD + c4;
        const float4 v = *(const float4*)(u + re);
        const float4 x = *(const float4*)(xin + re);
        acc[0] += v.x; acc[1] += v.y; acc[2] += v.z; acc[3] += v.w;
        float4 o;
        o.x = x.x + wr * v.x; o.y = x.y + wr * v.y;
        o.z = x.z + wr * v.z; o.w = x.w + wr * v.w;
        *(float4*)(u + re) = o;
    }
    *(f32x4*)&accl[sub * 128 + c4] = acc;
    __syncthreads();
    if (tid < 128) {
        float s = 0.f;
        #pragma unroll
        for (int q = 0; q < 8; ++q) s += accl[q * 128 + tid];
        aggp[((long)p * BG_ + bg) * DD + tid] = s;
    }
}

// ---------------- global block: 512 rows, K=384, fp32 VALU ----------------
__global__ __launch_bounds__(128) void global_block(
    const float* __restrict__ naggp, const float* __restrict__ eaggp,
    const float* __restrict__ glob,
    const float* __restrict__ Wg, const float* __restrict__ bgb,
    const float* __restrict__ w_res, float* __restrict__ out) {
    __shared__ float gin[384];
    const int row = blockIdx.x;
    const int tid = threadIdx.x;
    float sn = 0.f, se = 0.f;
    #pragma unroll
    for (int p = 0; p < PART; ++p) {
        sn += naggp[((long)p * BG_ + row) * DD + tid];
        se += eaggp[((long)p * BG_ + row) * DD + tid];
    }
    gin[tid]       = sn;
    gin[128 + tid] = se;
    gin[256 + tid] = glob[row * DD + tid];
    __syncthreads();
    float acc = bgb[tid];
    #pragma unroll 4
    for (int k = 0; k < 384; ++k) acc += gin[k] * Wg[k * DD + tid];
    const float upd = fmaxf(acc, 0.f);
    out[OFF_GLOB + row * DD + tid] = glob[row * DD + tid] + w_res[0] * upd;
}

extern "C" void kernel_launch(void* const* d_in, const int* in_sizes, int n_in,
                              void* d_out, int out_size, void* d_ws, size_t ws_size,
                              hipStream_t stream) {
    const float* nodes     = (const float*)d_in[0];
    const float* edges     = (const float*)d_in[1];
    const int*   receivers = (const int*)d_in[2];
    const int*   senders   = (const int*)d_in[3];
    const float* glob      = (const float*)d_in[4];
    const int*   ngi       = (const int*)d_in[5];
    const int*   egi       = (const int*)d_in[6];
    const float* We        = (const float*)d_in[7];
    const float* be        = (const float*)d_in[8];
    const float* Wn        = (const float*)d_in[9];
    const float* bn        = (const float*)d_in[10];
    const float* Wg        = (const float*)d_in[11];
    const float* bg        = (const float*)d_in[12];
    const float* w_res     = (const float*)d_in[13];
    float* out = (float*)d_out;
    float* ws  = (float*)d_ws;

    float* eaggp = ws + WS_EAGGP;
    float* naggp = ws + WS_NAGGP;
    int* cnt      = (int*)(ws + WS_CNT);
    int* gcnt_e   = (int*)(ws + WS_GCNTE);
    int* gcnt_n   = (int*)(ws + WS_GCNTN);
    int* cur      = (int*)(ws + WS_CUR);
    int* gcur_e   = (int*)(ws + WS_GCURE);
    int* gcur_n   = (int*)(ws + WS_GCURN);
    int* elist    = (int*)(ws + WS_ELIST);
    int* gelist_e = (int*)(ws + WS_GELE);
    int* gelist_n = (int*)(ws + WS_GELN);
    u16* adjB   = (u16*)(ws + WS_ADJB);
    u16* nodesB = (u16*)(ws + WS_NODB);
    u16* globB  = (u16*)(ws + WS_GLOBB);
    u16* WeT2   = (u16*)(ws + WS_WET);
    u16* WnT2   = (u16*)(ws + WS_WNT);
    u16* uEb    = (u16*)(ws + WS_UEB);

    float* outE = out + OFF_EDGES;   // edges_out written directly by edge_mfma
    float* uN   = out + OFF_NODES;   // u_n, becomes nodes_out after agg_resid

    hipLaunchKernelGGL(prep_w, dim3(448), dim3(256), 0, stream, We, Wn, WeT2, WnT2);
    hipLaunchKernelGGL(cast_bf16, dim3(2080), dim3(256), 0, stream,
                       nodes, glob, nodesB, globB);
    hipLaunchKernelGGL(init_misc, dim3(1796), dim3(256), 0, stream,
                       receivers, senders, ngi, egi, out, cnt);
    hipLaunchKernelGGL(k_hist_all, dim3(512), dim3(256), 0, stream,
                       receivers, egi, ngi, cnt, gcnt_e, gcnt_n);
    hipLaunchKernelGGL(k_scan, dim3(8), dim3(1024), 0, stream,
                       cnt, cur, gcnt_e, gcur_e, gcnt_n, gcur_n);
    hipLaunchKernelGGL(k_fill_all, dim3(512), dim3(256), 0, stream,
                       receivers, egi, ngi, cur, elist, gcur_e, gelist_e,
                       gcur_n, gelist_n);
    hipLaunchKernelGGL(edge_mfma, dim3(2048), dim3(256), 0, stream,
                       edges, nodesB, globB, receivers, senders, egi, WeT2, be,
                       w_res, outE, uEb);
    hipLaunchKernelGGL(adj_gather, dim3(BN_ / 64), dim3(256), 0, stream,
                       cur, cnt, elist, uEb, adjB);
    hipLaunchKernelGGL(agg_only, dim3(BG_ * PART), dim3(256), 0, stream,
                       gcnt_e, gcur_e, gelist_e, uEb, eaggp);
    hipLaunchKernelGGL(node_mfma, dim3(512), dim3(256), 0, stream,
                       nodesB, adjB, globB, ngi, WnT2, bn, uN);
    hipLaunchKernelGGL(agg_resid, dim3(BG_ * PART), dim3(256), 0, stream,
                       gcnt_n, gcur_n, gelist_n, N_, nodes, w_res, uN, naggp);
    hipLaunchKernelGGL(global_block, dim3(BG_), dim3(128), 0, stream,
                       naggp, eaggp, glob, Wg, bg, w_res, out);
}

// Round 11
// 228.143 us; speedup vs baseline: 1.1081x; 1.0222x over previous
//
#include <hip/hip_runtime.h>

// GraphNetworkLayer: B=8, N=4096, E=16384, G=64, D=128, fp32 in/out.
// Round 11:
//  - edge_mfma: __launch_bounds__(256,2) — LDS (64KB) caps at 2 blocks/CU
//    anyway, so grant the full 256-VGPR budget; all-upfront A prefetch now
//    fits live (KEEP4-pinned), killing the serialized latency round-trips.
//  - node_mfma: __launch_bounds__(256,3) (48KB LDS -> 3 blocks/CU), fused
//    residual epilogue (nodes_out direct + uNb bf16 into the consumed uEb
//    ws region); agg_resid(n) replaced by agg_only(n).
//  - prep_w + cast_bf16 + init_misc merged into prep_all (10 launches).
// No float atomics anywhere.

#define DD 128
typedef unsigned short u16;
typedef __attribute__((ext_vector_type(8))) short short8;   // 8 bf16
typedef __attribute__((ext_vector_type(4))) short s16x4;    // 4 bf16
typedef __attribute__((ext_vector_type(4))) float f32x4;

constexpr int B_ = 8, N_ = 4096, E_ = 16384, G_ = 64;
constexpr int NODES_SZ = B_ * N_ * DD;   // 4,194,304
constexpr int EDGES_SZ = B_ * E_ * DD;   // 16,777,216
constexpr int BE_ = B_ * E_;             // 131,072
constexpr int BN_ = B_ * N_;             // 32,768
constexpr int BG_ = B_ * G_;             // 512
constexpr int GLOB_SZ = BG_ * DD;        // 65,536
constexpr int PART = 4;

constexpr int OFF_NODES = 0;
constexpr int OFF_EDGES = OFF_NODES + NODES_SZ;
constexpr int OFF_RECV  = OFF_EDGES + EDGES_SZ;
constexpr int OFF_SEND  = OFF_RECV + BE_;
constexpr int OFF_GLOB  = OFF_SEND + BE_;
constexpr int OFF_NGI   = OFF_GLOB + GLOB_SZ;
constexpr int OFF_EGI   = OFF_NGI + BN_;

// ws layout (float-element offsets) — same extent as R10 (~54 MB)
constexpr int WS_EAGGP = 0;                          // [PART][BG][DD] f32
constexpr int WS_NAGGP = WS_EAGGP + PART * GLOB_SZ;
constexpr int WS_CNT   = WS_NAGGP + PART * GLOB_SZ;  // int [B*N] (zeroed)
constexpr int WS_GCNTE = WS_CNT + BN_;               // int [512] (zeroed)
constexpr int WS_GCNTN = WS_GCNTE + 512;             // int [512] (zeroed)
constexpr int WS_CUR   = WS_GCNTN + 512;             // int [B*N]
constexpr int WS_GCURE = WS_CUR + BN_;               // int [512]
constexpr int WS_GCURN = WS_GCURE + 512;             // int [512]
constexpr int WS_ELIST = WS_GCURN + 512;             // int [B*E]
constexpr int WS_GELE  = WS_ELIST + BE_;             // int [B*E]
constexpr int WS_GELN  = WS_GELE + BE_;              // int [B*N]
constexpr int WS_ADJB  = WS_GELN + BN_;              // u16 [B,N,D]
constexpr int WS_NODB  = WS_ADJB + (BN_ * DD) / 2;   // u16 [B,N,D]
constexpr int WS_GLOBB = WS_NODB + (BN_ * DD) / 2;   // u16 [B,G,D]
constexpr int WS_WET   = WS_GLOBB + GLOB_SZ / 2;     // u16 [128*512] swz image
constexpr int WS_WNT   = WS_WET + 32768;             // u16 [128*384] swz image
constexpr int WS_UEB   = WS_WNT + 24576;             // u16 [B,E,D] bf16 u_e
// uNb (u16 [B,N,D]) aliases the START of WS_UEB: uEb is fully consumed by
// adj_gather + agg_only(e) BEFORE node_mfma writes uNb (stream-ordered).

__device__ inline u16 f2bf(float f) {
    union { float f; unsigned u; } v; v.f = f;
    return (u16)((v.u + 0x7fffu + ((v.u >> 16) & 1u)) >> 16);
}
__device__ inline float bf2f(u16 h) {
    union { unsigned u; float f; } v; v.u = ((unsigned)h) << 16; return v.f;
}
__device__ inline short8 pack8(float4 a, float4 b) {
    short8 r;
    r[0] = (short)f2bf(a.x); r[1] = (short)f2bf(a.y);
    r[2] = (short)f2bf(a.z); r[3] = (short)f2bf(a.w);
    r[4] = (short)f2bf(b.x); r[5] = (short)f2bf(b.y);
    r[6] = (short)f2bf(b.z); r[7] = (short)f2bf(b.w);
    return r;
}

#define KEEP4(a0, a1, a2, a3) \
    asm volatile("" :: "v"(a0), "v"(a1), "v"(a2), "v"(a3))

// -------- fused prep: weight swizzle-images + bf16 casts + idx copies + zero
__global__ __launch_bounds__(256) void prep_all(
    const float* __restrict__ We, const float* __restrict__ Wn,
    u16* __restrict__ WeT2, u16* __restrict__ WnT2,
    const float* __restrict__ nodes, const float* __restrict__ glob,
    u16* __restrict__ nodesB, u16* __restrict__ globB,
    const int* __restrict__ recv, const int* __restrict__ send,
    const int* __restrict__ ngi, const int* __restrict__ egi,
    float* __restrict__ out, int* __restrict__ zbase) {
    const int i = blockIdx.x * 256 + threadIdx.x;
    if (i < 114688) {
        if (i < 65536) {
            const int ch = i >> 15;
            const int r = i & 32767;
            const int row = r >> 9;
            const int inb = (r << 1) & 1023;
            const int kb = inb ^ ((row & 7) << 4);
            WeT2[i] = f2bf(We[(kb >> 1) * DD + ch * 64 + row]);
        } else {
            const int q = i - 65536;
            const int ch = q / 24576;
            const int r = q % 24576;
            const int row = r / 384;
            const int inb = (r % 384) << 1;
            const int kb = inb ^ ((row & 7) << 4);
            WnT2[q] = f2bf(Wn[(kb >> 1) * DD + ch * 64 + row]);
        }
    } else if (i < 647168) {
        const int j = i - 114688;
        const int NT = NODES_SZ / 8;
        if (j < NT) {
            const float4 a = *(const float4*)(nodes + (long)j * 8);
            const float4 b = *(const float4*)(nodes + (long)j * 8 + 4);
            *(short8*)(nodesB + (long)j * 8) = pack8(a, b);
        } else {
            const int j2 = j - NT;
            const float4 a = *(const float4*)(glob + (long)j2 * 8);
            const float4 b = *(const float4*)(glob + (long)j2 * 8 + 4);
            *(short8*)(globB + (long)j2 * 8) = pack8(a, b);
        }
    } else if (i < 1073152) {
        const int k2 = i - 647168;
        if (k2 < BE_)                 out[OFF_RECV + k2] = (float)recv[k2];
        else if (k2 < 2 * BE_)        out[OFF_SEND + (k2 - BE_)] = (float)send[k2 - BE_];
        else if (k2 < 2 * BE_ + BN_)  out[OFF_NGI + (k2 - 2 * BE_)] = (float)ngi[k2 - 2 * BE_];
        else                          out[OFF_EGI + (k2 - 2 * BE_ - BN_)] = (float)egi[k2 - 2 * BE_ - BN_];
    } else {
        zbase[i - 1073152] = 0;   // BN_ + 1024 ints, grid sized exactly
    }
}

__global__ __launch_bounds__(256) void k_hist_all(
    const int* __restrict__ recv, const int* __restrict__ egi,
    const int* __restrict__ ngi,
    int* __restrict__ cnt, int* __restrict__ gcnt_e, int* __restrict__ gcnt_n) {
    const int i = blockIdx.x * 256 + threadIdx.x;
    const int b = i >> 14;
    atomicAdd(&cnt[b * N_ + recv[i]], 1);
    atomicAdd(&gcnt_e[b * G_ + egi[i]], 1);
    if (i < BN_) atomicAdd(&gcnt_n[(i >> 12) * G_ + ngi[i]], 1);
}

__global__ __launch_bounds__(1024) void k_scan(
    const int* __restrict__ cnt, int* __restrict__ cur,
    const int* __restrict__ gcnt_e, int* __restrict__ gcur_e,
    const int* __restrict__ gcnt_n, int* __restrict__ gcur_n) {
    __shared__ int s[1024];
    const int b = blockIdx.x;
    const int t = threadIdx.x;
    const int base = b * N_;
    int c[4];
    int sum = 0;
    #pragma unroll
    for (int i = 0; i < 4; ++i) { c[i] = cnt[base + 4 * t + i]; sum += c[i]; }
    s[t] = sum;
    __syncthreads();
    for (int off = 1; off < 1024; off <<= 1) {
        int v = s[t];
        if (t >= off) v += s[t - off];
        __syncthreads();
        s[t] = v;
        __syncthreads();
    }
    int eb = s[t] - sum;
    #pragma unroll
    for (int i = 0; i < 4; ++i) { cur[base + 4 * t + i] = eb; eb += c[i]; }
    __syncthreads();
    int gv = 0;
    if (t < G_) { gv = gcnt_e[b * G_ + t]; s[t] = gv; }
    __syncthreads();
    for (int off = 1; off < G_; off <<= 1) {
        int v = 0;
        if (t < G_) { v = s[t]; if (t >= off) v += s[t - off]; }
        __syncthreads();
        if (t < G_) s[t] = v;
        __syncthreads();
    }
    if (t < G_) gcur_e[b * G_ + t] = s[t] - gv;
    __syncthreads();
    if (t < G_) { gv = gcnt_n[b * G_ + t]; s[t] = gv; }
    __syncthreads();
    for (int off = 1; off < G_; off <<= 1) {
        int v = 0;
        if (t < G_) { v = s[t]; if (t >= off) v += s[t - off]; }
        __syncthreads();
        if (t < G_) s[t] = v;
        __syncthreads();
    }
    if (t < G_) gcur_n[b * G_ + t] = s[t] - gv;
}

__global__ __launch_bounds__(256) void k_fill_all(
    const int* __restrict__ recv, const int* __restrict__ egi,
    const int* __restrict__ ngi,
    int* __restrict__ cur, int* __restrict__ elist,
    int* __restrict__ gcur_e, int* __restrict__ gelist_e,
    int* __restrict__ gcur_n, int* __restrict__ gelist_n) {
    const int i = blockIdx.x * 256 + threadIdx.x;
    const int b = i >> 14;
    const int s1 = atomicAdd(&cur[b * N_ + recv[i]], 1);
    elist[b * E_ + s1] = i;
    const int s2 = atomicAdd(&gcur_e[b * G_ + egi[i]], 1);
    gelist_e[b * E_ + s2] = i;
    if (i < BN_) {
        const int b2 = i >> 12;
        const int s3 = atomicAdd(&gcur_n[b2 * G_ + ngi[i]], 1);
        gelist_n[b2 * N_ + s3] = i;
    }
}

// -------- edge GEMM: B async-LDS, A reg-resident; VGPR budget granted by
// __launch_bounds__(256,2) (LDS already caps at 2 blocks/CU).
__global__ __launch_bounds__(256, 2) void edge_mfma(
    const float* __restrict__ edges, const u16* __restrict__ nodesB,
    const u16* __restrict__ globB,
    const int* __restrict__ receivers, const int* __restrict__ senders,
    const int* __restrict__ egi,
    const u16* __restrict__ WeT2, const float* __restrict__ be,
    const float* __restrict__ w_res,
    float* __restrict__ outE, u16* __restrict__ uEb) {
    __shared__ u16 Bs[64 * 512];               // 64 KB pre-swizzled B image
    const int tid = threadIdx.x;
    const int bid = blockIdx.x;                // 2048
    const int bb = bid & 7;                    // batch = XCD
    const int jj = bid >> 3;                   // 0..255
    const int ch = jj & 1;
    const int rt = jj >> 1;                    // 0..127
    const int row0 = bb * E_ + rt * 128;

    const int wv = tid >> 6, l = tid & 63;
    const int fr = l & 15, fg = l >> 4;
    const int rowbase = row0 + wv * 32;
    const int R0 = rowbase + fr, R1 = R0 + 16;

    // async B staging: 16 x 1KB per wave, linear dest (image pre-swizzled)
    {
        const char* wsrc = (const char*)(WeT2 + (long)ch * 32768) + l * 16;
        char* ldst = (char*)Bs;
        #pragma unroll
        for (int i2 = 0; i2 < 16; ++i2) {
            const int off = (wv * 16 + i2) * 1024;
            __builtin_amdgcn_global_load_lds(
                (const __attribute__((address_space(1))) void*)(wsrc + off),
                (__attribute__((address_space(3))) void*)(ldst + off),
                16, 0, 0);
        }
    }

    // A gathers: ALL segments, pinned in regs by keep-alive before barrier
    const float* pE0 = edges + (long)R0 * DD;
    const float* pE1 = edges + (long)R1 * DD;
    const u16* nb = nodesB + (long)bb * (N_ * DD);
    const u16* aps0[3] = { nb + (long)senders[R0] * DD,
                           nb + (long)receivers[R0] * DD,
                           globB + ((long)bb * G_ + egi[R0]) * DD };
    const u16* aps1[3] = { nb + (long)senders[R1] * DD,
                           nb + (long)receivers[R1] * DD,
                           globB + ((long)bb * G_ + egi[R1]) * DD };
    short8 P0[3][4], P1[3][4];
    #pragma unroll
    for (int s = 0; s < 3; ++s) {
        #pragma unroll
        for (int ss = 0; ss < 4; ++ss) {
            P0[s][ss] = *(const short8*)(aps0[s] + ss * 32 + fg * 8);
            P1[s][ss] = *(const short8*)(aps1[s] + ss * 32 + fg * 8);
        }
    }
    short8 A0[4], A1[4];
    #pragma unroll
    for (int ss = 0; ss < 4; ++ss) {
        const int off = ss * 32 + fg * 8;
        A0[ss] = pack8(*(const float4*)(pE0 + off), *(const float4*)(pE0 + off + 4));
        A1[ss] = pack8(*(const float4*)(pE1 + off), *(const float4*)(pE1 + off + 4));
    }

    KEEP4(P0[0][0], P0[0][1], P0[0][2], P0[0][3]);
    KEEP4(P0[1][0], P0[1][1], P0[1][2], P0[1][3]);
    KEEP4(P0[2][0], P0[2][1], P0[2][2], P0[2][3]);
    KEEP4(P1[0][0], P1[0][1], P1[0][2], P1[0][3]);
    KEEP4(P1[1][0], P1[1][1], P1[1][2], P1[1][3]);
    KEEP4(P1[2][0], P1[2][1], P1[2][2], P1[2][3]);
    KEEP4(A0[0], A0[1], A0[2], A0[3]);
    KEEP4(A1[0], A1[1], A1[2], A1[3]);

    f32x4 acc0[4], acc1[4];
    const f32x4 fz = {0.f, 0.f, 0.f, 0.f};
    #pragma unroll
    for (int i = 0; i < 4; ++i) { acc0[i] = fz; acc1[i] = fz; }

    __syncthreads();   // vmcnt(0) drain: B in LDS, all A in regs

    // K loop: pure ds_read_b128 + MFMA
    const char* bsp = (const char*)Bs;
    const int swr = (fr & 7) << 4;
    #pragma unroll
    for (int seg = 0; seg < 4; ++seg) {
        __builtin_amdgcn_s_setprio(1);
        #pragma unroll
        for (int ss = 0; ss < 4; ++ss) {
            short8 bfr[4];
            #pragma unroll
            for (int nt = 0; nt < 4; ++nt) {
                const int addr = (nt * 16 + fr) * 1024 +
                                 ((seg * 256 + ss * 64 + fg * 16) ^ swr);
                bfr[nt] = *(const short8*)(bsp + addr);
            }
            #pragma unroll
            for (int nt = 0; nt < 4; ++nt) {
                acc0[nt] = __builtin_amdgcn_mfma_f32_16x16x32_bf16(bfr[nt], A0[ss], acc0[nt], 0, 0, 0);
                acc1[nt] = __builtin_amdgcn_mfma_f32_16x16x32_bf16(bfr[nt], A1[ss], acc1[nt], 0, 0, 0);
            }
        }
        __builtin_amdgcn_s_setprio(0);
        if (seg < 3) {
            #pragma unroll
            for (int ss = 0; ss < 4; ++ss) { A0[ss] = P0[seg][ss]; A1[ss] = P1[seg][ss]; }
        }
    }

    // fused-residual epilogue: lane owns cols c..c+3 at rows R0/R1
    const float wr = w_res[0];
    #pragma unroll
    for (int nt = 0; nt < 4; ++nt) {
        const int c = ch * 64 + nt * 16 + fg * 4;
        const float4 bv = *(const float4*)(be + c);
        const float4 e0 = *(const float4*)(edges + (long)R0 * DD + c);
        const float4 e1 = *(const float4*)(edges + (long)R1 * DD + c);
        const float u00 = fmaxf(acc0[nt][0] + bv.x, 0.f);
        const float u01 = fmaxf(acc0[nt][1] + bv.y, 0.f);
        const float u02 = fmaxf(acc0[nt][2] + bv.z, 0.f);
        const float u03 = fmaxf(acc0[nt][3] + bv.w, 0.f);
        const float u10 = fmaxf(acc1[nt][0] + bv.x, 0.f);
        const float u11 = fmaxf(acc1[nt][1] + bv.y, 0.f);
        const float u12 = fmaxf(acc1[nt][2] + bv.z, 0.f);
        const float u13 = fmaxf(acc1[nt][3] + bv.w, 0.f);
        s16x4 h0, h1;
        h0[0] = (short)f2bf(u00); h0[1] = (short)f2bf(u01);
        h0[2] = (short)f2bf(u02); h0[3] = (short)f2bf(u03);
        h1[0] = (short)f2bf(u10); h1[1] = (short)f2bf(u11);
        h1[2] = (short)f2bf(u12); h1[3] = (short)f2bf(u13);
        *(s16x4*)(uEb + (long)R0 * DD + c) = h0;
        *(s16x4*)(uEb + (long)R1 * DD + c) = h1;
        float4 o0, o1;
        o0.x = e0.x + wr * u00; o0.y = e0.y + wr * u01;
        o0.z = e0.z + wr * u02; o0.w = e0.w + wr * u03;
        o1.x = e1.x + wr * u10; o1.y = e1.y + wr * u11;
        o1.z = e1.z + wr * u12; o1.w = e1.w + wr * u13;
        *(float4*)(outE + (long)R0 * DD + c) = o0;
        *(float4*)(outE + (long)R1 * DD + c) = o1;
    }
}

// -------- adj = CSR gather-sum of bf16 u_e rows -> bf16 adjB --------
__global__ __launch_bounds__(256) void adj_gather(
    const int* __restrict__ cur, const int* __restrict__ cnt,
    const int* __restrict__ elist, const u16* __restrict__ uEb,
    u16* __restrict__ adjB) {
    const int tid = threadIdx.x;
    const int row = blockIdx.x * 64 + (tid >> 2);
    const int q = tid & 3;
    const int bb = row >> 12;
    const int deg = cnt[row];
    const int start = cur[row] - deg;
    const int* lp = elist + (long)bb * E_ + start;
    float a[32];
    #pragma unroll
    for (int j = 0; j < 32; ++j) a[j] = 0.f;
    for (int i = 0; i < deg; ++i) {
        const u16* up = uEb + (long)lp[i] * DD + q * 32;
        #pragma unroll
        for (int j = 0; j < 4; ++j) {
            const short8 v = *(const short8*)(up + j * 8);
            #pragma unroll
            for (int e2 = 0; e2 < 8; ++e2) a[j * 8 + e2] += bf2f((u16)v[e2]);
        }
    }
    u16* dst = adjB + (long)row * DD + q * 32;
    #pragma unroll
    for (int j = 0; j < 4; ++j) {
        short8 h;
        #pragma unroll
        for (int e2 = 0; e2 < 8; ++e2) h[e2] = (short)f2bf(a[j * 8 + e2]);
        *(short8*)(dst + j * 8) = h;
    }
}

// -------- agg = per-(b,g) gather-sum of bf16 u rows --------
__global__ __launch_bounds__(256) void agg_only(
    const int* __restrict__ gcnt, const int* __restrict__ gcur,
    const int* __restrict__ gelist, int spb, const u16* __restrict__ uB,
    float* __restrict__ aggp /* [PART][BG][DD] */) {
    __shared__ float accl[1024];
    const int bg = blockIdx.x >> 2;            // grid = BG*PART
    const int p  = blockIdx.x & 3;
    const int b = bg >> 6;
    const int tid = threadIdx.x;
    const int c4 = (tid & 31) << 2;
    const int sub = tid >> 5;                  // 0..7
    const int m = gcnt[bg];
    const int* lp = gelist + (long)b * spb + (gcur[bg] - m);
    f32x4 acc = {0.f, 0.f, 0.f, 0.f};
    for (int j = p * 8 + sub; j < m; j += 32) {
        const u16* up = uB + (long)lp[j] * DD + c4;
        const s16x4 v = *(const s16x4*)up;
        acc[0] += bf2f((u16)v[0]); acc[1] += bf2f((u16)v[1]);
        acc[2] += bf2f((u16)v[2]); acc[3] += bf2f((u16)v[3]);
    }
    *(f32x4*)&accl[sub * 128 + c4] = acc;
    __syncthreads();
    if (tid < 128) {
        float s = 0.f;
        #pragma unroll
        for (int q = 0; q < 8; ++q) s += accl[q * 128 + tid];
        aggp[((long)p * BG_ + bg) * DD + tid] = s;
    }
}

// -------- node GEMM: fused residual epilogue, (256,3) --------
__global__ __launch_bounds__(256, 3) void node_mfma(
    const u16* __restrict__ nodesB, const u16* __restrict__ adjB,
    const u16* __restrict__ globB, const int* __restrict__ ngi,
    const u16* __restrict__ WnT2, const float* __restrict__ bn,
    const float* __restrict__ nodes, const float* __restrict__ w_res,
    float* __restrict__ outN, u16* __restrict__ uNb) {
    __shared__ u16 Bs[64 * 384];               // 48 KB pre-swizzled B image
    const int tid = threadIdx.x;
    const int bid = blockIdx.x;                // 512
    const int bb = bid & 7;
    const int jj = bid >> 3;                   // 0..63
    const int ch = jj & 1;
    const int rt = jj >> 1;                    // 0..31
    const int row0 = bb * N_ + rt * 128;

    const int wv = tid >> 6, l = tid & 63;
    const int fr = l & 15, fg = l >> 4;
    const int rowbase = row0 + wv * 32;
    const int R0 = rowbase + fr, R1 = R0 + 16;

    {
        const char* wsrc = (const char*)(WnT2 + (long)ch * 24576) + l * 16;
        char* ldst = (char*)Bs;
        #pragma unroll
        for (int i2 = 0; i2 < 12; ++i2) {
            const int off = (wv * 12 + i2) * 1024;
            __builtin_amdgcn_global_load_lds(
                (const __attribute__((address_space(1))) void*)(wsrc + off),
                (__attribute__((address_space(3))) void*)(ldst + off),
                16, 0, 0);
        }
    }

    const u16* aps0[3] = { nodesB + (long)R0 * DD, adjB + (long)R0 * DD,
                           globB + ((long)bb * G_ + ngi[R0]) * DD };
    const u16* aps1[3] = { nodesB + (long)R1 * DD, adjB + (long)R1 * DD,
                           globB + ((long)bb * G_ + ngi[R1]) * DD };
    short8 P0[3][4], P1[3][4];
    #pragma unroll
    for (int s = 0; s < 3; ++s) {
        #pragma unroll
        for (int ss = 0; ss < 4; ++ss) {
            P0[s][ss] = *(const short8*)(aps0[s] + ss * 32 + fg * 8);
            P1[s][ss] = *(const short8*)(aps1[s] + ss * 32 + fg * 8);
        }
    }
    KEEP4(P0[0][0], P0[0][1], P0[0][2], P0[0][3]);
    KEEP4(P0[1][0], P0[1][1], P0[1][2], P0[1][3]);
    KEEP4(P0[2][0], P0[2][1], P0[2][2], P0[2][3]);
    KEEP4(P1[0][0], P1[0][1], P1[0][2], P1[0][3]);
    KEEP4(P1[1][0], P1[1][1], P1[1][2], P1[1][3]);
    KEEP4(P1[2][0], P1[2][1], P1[2][2], P1[2][3]);

    f32x4 acc0[4], acc1[4];
    const f32x4 fz = {0.f, 0.f, 0.f, 0.f};
    #pragma unroll
    for (int i = 0; i < 4; ++i) { acc0[i] = fz; acc1[i] = fz; }

    __syncthreads();

    const char* bsp = (const char*)Bs;
    const int swr = (fr & 7) << 4;
    #pragma unroll
    for (int seg = 0; seg < 3; ++seg) {
        __builtin_amdgcn_s_setprio(1);
        #pragma unroll
        for (int ss = 0; ss < 4; ++ss) {
            short8 bfr[4];
            #pragma unroll
            for (int nt = 0; nt < 4; ++nt) {
                const int addr = (nt * 16 + fr) * 768 +
                                 ((seg * 256 + ss * 64 + fg * 16) ^ swr);
                bfr[nt] = *(const short8*)(bsp + addr);
            }
            #pragma unroll
            for (int nt = 0; nt < 4; ++nt) {
                acc0[nt] = __builtin_amdgcn_mfma_f32_16x16x32_bf16(bfr[nt], P0[seg][ss], acc0[nt], 0, 0, 0);
                acc1[nt] = __builtin_amdgcn_mfma_f32_16x16x32_bf16(bfr[nt], P1[seg][ss], acc1[nt], 0, 0, 0);
            }
        }
        __builtin_amdgcn_s_setprio(0);
    }

    const float wr = w_res[0];
    #pragma unroll
    for (int nt = 0; nt < 4; ++nt) {
        const int c = ch * 64 + nt * 16 + fg * 4;
        const float4 bv = *(const float4*)(bn + c);
        const float4 n0 = *(const float4*)(nodes + (long)R0 * DD + c);
        const float4 n1 = *(const float4*)(nodes + (long)R1 * DD + c);
        const float u00 = fmaxf(acc0[nt][0] + bv.x, 0.f);
        const float u01 = fmaxf(acc0[nt][1] + bv.y, 0.f);
        const float u02 = fmaxf(acc0[nt][2] + bv.z, 0.f);
        const float u03 = fmaxf(acc0[nt][3] + bv.w, 0.f);
        const float u10 = fmaxf(acc1[nt][0] + bv.x, 0.f);
        const float u11 = fmaxf(acc1[nt][1] + bv.y, 0.f);
        const float u12 = fmaxf(acc1[nt][2] + bv.z, 0.f);
        const float u13 = fmaxf(acc1[nt][3] + bv.w, 0.f);
        s16x4 h0, h1;
        h0[0] = (short)f2bf(u00); h0[1] = (short)f2bf(u01);
        h0[2] = (short)f2bf(u02); h0[3] = (short)f2bf(u03);
        h1[0] = (short)f2bf(u10); h1[1] = (short)f2bf(u11);
        h1[2] = (short)f2bf(u12); h1[3] = (short)f2bf(u13);
        *(s16x4*)(uNb + (long)R0 * DD + c) = h0;
        *(s16x4*)(uNb + (long)R1 * DD + c) = h1;
        float4 o0, o1;
        o0.x = n0.x + wr * u00; o0.y = n0.y + wr * u01;
        o0.z = n0.z + wr * u02; o0.w = n0.w + wr * u03;
        o1.x = n1.x + wr * u10; o1.y = n1.y + wr * u11;
        o1.z = n1.z + wr * u12; o1.w = n1.w + wr * u13;
        *(float4*)(outN + (long)R0 * DD + c) = o0;
        *(float4*)(outN + (long)R1 * DD + c) = o1;
    }
}

// ---------------- global block: 512 rows, K=384, fp32 VALU ----------------
__global__ __launch_bounds__(128) void global_block(
    const float* __restrict__ naggp, const float* __restrict__ eaggp,
    const float* __restrict__ glob,
    const float* __restrict__ Wg, const float* __restrict__ bgb,
    const float* __restrict__ w_res, float* __restrict__ out) {
    __shared__ float gin[384];
    const int row = blockIdx.x;
    const int tid = threadIdx.x;
    float sn = 0.f, se = 0.f;
    #pragma unroll
    for (int p = 0; p < PART; ++p) {
        sn += naggp[((long)p * BG_ + row) * DD + tid];
        se += eaggp[((long)p * BG_ + row) * DD + tid];
    }
    gin[tid]       = sn;
    gin[128 + tid] = se;
    gin[256 + tid] = glob[row * DD + tid];
    __syncthreads();
    float acc = bgb[tid];
    #pragma unroll 4
    for (int k = 0; k < 384; ++k) acc += gin[k] * Wg[k * DD + tid];
    const float upd = fmaxf(acc, 0.f);
    out[OFF_GLOB + row * DD + tid] = glob[row * DD + tid] + w_res[0] * upd;
}

extern "C" void kernel_launch(void* const* d_in, const int* in_sizes, int n_in,
                              void* d_out, int out_size, void* d_ws, size_t ws_size,
                              hipStream_t stream) {
    const float* nodes     = (const float*)d_in[0];
    const float* edges     = (const float*)d_in[1];
    const int*   receivers = (const int*)d_in[2];
    const int*   senders   = (const int*)d_in[3];
    const float* glob      = (const float*)d_in[4];
    const int*   ngi       = (const int*)d_in[5];
    const int*   egi       = (const int*)d_in[6];
    const float* We        = (const float*)d_in[7];
    const float* be        = (const float*)d_in[8];
    const float* Wn        = (const float*)d_in[9];
    const float* bn        = (const float*)d_in[10];
    const float* Wg        = (const float*)d_in[11];
    const float* bg        = (const float*)d_in[12];
    const float* w_res     = (const float*)d_in[13];
    float* out = (float*)d_out;
    float* ws  = (float*)d_ws;

    float* eaggp = ws + WS_EAGGP;
    float* naggp = ws + WS_NAGGP;
    int* cnt      = (int*)(ws + WS_CNT);
    int* gcnt_e   = (int*)(ws + WS_GCNTE);
    int* gcnt_n   = (int*)(ws + WS_GCNTN);
    int* cur      = (int*)(ws + WS_CUR);
    int* gcur_e   = (int*)(ws + WS_GCURE);
    int* gcur_n   = (int*)(ws + WS_GCURN);
    int* elist    = (int*)(ws + WS_ELIST);
    int* gelist_e = (int*)(ws + WS_GELE);
    int* gelist_n = (int*)(ws + WS_GELN);
    u16* adjB   = (u16*)(ws + WS_ADJB);
    u16* nodesB = (u16*)(ws + WS_NODB);
    u16* globB  = (u16*)(ws + WS_GLOBB);
    u16* WeT2   = (u16*)(ws + WS_WET);
    u16* WnT2   = (u16*)(ws + WS_WNT);
    u16* uEb    = (u16*)(ws + WS_UEB);
    u16* uNb    = uEb;               // aliases: uEb fully consumed first

    float* outE = out + OFF_EDGES;
    float* outN = out + OFF_NODES;

    hipLaunchKernelGGL(prep_all, dim3(4324), dim3(256), 0, stream,
                       We, Wn, WeT2, WnT2, nodes, glob, nodesB, globB,
                       receivers, senders, ngi, egi, out, cnt);
    hipLaunchKernelGGL(k_hist_all, dim3(512), dim3(256), 0, stream,
                       receivers, egi, ngi, cnt, gcnt_e, gcnt_n);
    hipLaunchKernelGGL(k_scan, dim3(8), dim3(1024), 0, stream,
                       cnt, cur, gcnt_e, gcur_e, gcnt_n, gcur_n);
    hipLaunchKernelGGL(k_fill_all, dim3(512), dim3(256), 0, stream,
                       receivers, egi, ngi, cur, elist, gcur_e, gelist_e,
                       gcur_n, gelist_n);
    hipLaunchKernelGGL(edge_mfma, dim3(2048), dim3(256), 0, stream,
                       edges, nodesB, globB, receivers, senders, egi, WeT2, be,
                       w_res, outE, uEb);
    hipLaunchKernelGGL(adj_gather, dim3(BN_ / 64), dim3(256), 0, stream,
                       cur, cnt, elist, uEb, adjB);
    hipLaunchKernelGGL(agg_only, dim3(BG_ * PART), dim3(256), 0, stream,
                       gcnt_e, gcur_e, gelist_e, E_, uEb, eaggp);
    hipLaunchKernelGGL(node_mfma, dim3(512), dim3(256), 0, stream,
                       nodesB, adjB, globB, ngi, WnT2, bn, nodes, w_res,
                       outN, uNb);
    hipLaunchKernelGGL(agg_only, dim3(BG_ * PART), dim3(256), 0, stream,
                       gcnt_n, gcur_n, gelist_n, N_, uNb, naggp);
    hipLaunchKernelGGL(global_block, dim3(BG_), dim3(128), 0, stream,
                       naggp, eaggp, glob, Wg, bg, w_res, out);
}

// Round 12
// 225.483 us; speedup vs baseline: 1.1211x; 1.0118x over previous
//
#include <hip/hip_runtime.h>

// GraphNetworkLayer: B=8, N=4096, E=16384, G=64, D=128, fp32 in/out.
// Round 12: fully structural staging in edge_mfma.
//  - A seg-tiles (edgesB/senderB/recvB/globB rows) gather-staged into LDS via
//    global_load_lds with PER-LANE source addresses (swizzle pre-applied on
//    the source, linear LDS dest, XOR swizzle on ds_read — rule-21 pattern).
//  - B staged per K-half (32KB) from pre-swizzled WeT2 image.
//  - LDS 48KB -> 3 blocks/CU; K-loop is pure ds_read_b128+MFMA; compiler
//    cannot sink/remat any of it. Residual source captured from seg0 LDS
//    into registers (LDS loads are not rematerializable).
//  - edges pre-cast to bf16 (edgesB) in prep_all; edge kernel reads are all
//    L2/L3-hot, writes (outE+uEb ~100MB) are its floor.
// Node path and all scatter/agg kernels unchanged from R11 (passed).

#define DD 128
typedef unsigned short u16;
typedef __attribute__((ext_vector_type(8))) short short8;   // 8 bf16
typedef __attribute__((ext_vector_type(4))) short s16x4;    // 4 bf16
typedef __attribute__((ext_vector_type(4))) float f32x4;

constexpr int B_ = 8, N_ = 4096, E_ = 16384, G_ = 64;
constexpr int NODES_SZ = B_ * N_ * DD;   // 4,194,304
constexpr int EDGES_SZ = B_ * E_ * DD;   // 16,777,216
constexpr int BE_ = B_ * E_;             // 131,072
constexpr int BN_ = B_ * N_;             // 32,768
constexpr int BG_ = B_ * G_;             // 512
constexpr int GLOB_SZ = BG_ * DD;        // 65,536
constexpr int PART = 4;

constexpr int OFF_NODES = 0;
constexpr int OFF_EDGES = OFF_NODES + NODES_SZ;
constexpr int OFF_RECV  = OFF_EDGES + EDGES_SZ;
constexpr int OFF_SEND  = OFF_RECV + BE_;
constexpr int OFF_GLOB  = OFF_SEND + BE_;
constexpr int OFF_NGI   = OFF_GLOB + GLOB_SZ;
constexpr int OFF_EGI   = OFF_NGI + BN_;

// ws layout (float-element offsets)
constexpr int WS_EAGGP = 0;                          // [PART][BG][DD] f32
constexpr int WS_NAGGP = WS_EAGGP + PART * GLOB_SZ;
constexpr int WS_CNT   = WS_NAGGP + PART * GLOB_SZ;  // int [B*N] (zeroed)
constexpr int WS_GCNTE = WS_CNT + BN_;               // int [512] (zeroed)
constexpr int WS_GCNTN = WS_GCNTE + 512;             // int [512] (zeroed)
constexpr int WS_CUR   = WS_GCNTN + 512;             // int [B*N]
constexpr int WS_GCURE = WS_CUR + BN_;               // int [512]
constexpr int WS_GCURN = WS_GCURE + 512;             // int [512]
constexpr int WS_ELIST = WS_GCURN + 512;             // int [B*E]
constexpr int WS_GELE  = WS_ELIST + BE_;             // int [B*E]
constexpr int WS_GELN  = WS_GELE + BE_;              // int [B*N]
constexpr int WS_ADJB  = WS_GELN + BN_;              // u16 [B,N,D]
constexpr int WS_NODB  = WS_ADJB + (BN_ * DD) / 2;   // u16 [B,N,D]
constexpr int WS_GLOBB = WS_NODB + (BN_ * DD) / 2;   // u16 [B,G,D]
constexpr int WS_WET   = WS_GLOBB + GLOB_SZ / 2;     // u16 [128*512] swz image
constexpr int WS_WNT   = WS_WET + 32768;             // u16 [128*384] swz image
constexpr int WS_UEB   = WS_WNT + 24576;             // u16 [B,E,D] bf16 u_e
constexpr int WS_EDGB  = WS_UEB + (BE_ * DD) / 2;    // u16 [B,E,D] bf16 edges

__device__ inline u16 f2bf(float f) {
    union { float f; unsigned u; } v; v.f = f;
    return (u16)((v.u + 0x7fffu + ((v.u >> 16) & 1u)) >> 16);
}
__device__ inline float bf2f(u16 h) {
    union { unsigned u; float f; } v; v.u = ((unsigned)h) << 16; return v.f;
}
__device__ inline short8 pack8(float4 a, float4 b) {
    short8 r;
    r[0] = (short)f2bf(a.x); r[1] = (short)f2bf(a.y);
    r[2] = (short)f2bf(a.z); r[3] = (short)f2bf(a.w);
    r[4] = (short)f2bf(b.x); r[5] = (short)f2bf(b.y);
    r[6] = (short)f2bf(b.z); r[7] = (short)f2bf(b.w);
    return r;
}

// -------- fused prep: weight swizzle-images + bf16 casts (incl. edges) +
// idx passthrough + zero counters. grid = 12516 x 256.
__global__ __launch_bounds__(256) void prep_all(
    const float* __restrict__ We, const float* __restrict__ Wn,
    u16* __restrict__ WeT2, u16* __restrict__ WnT2,
    const float* __restrict__ nodes, const float* __restrict__ glob,
    const float* __restrict__ edges,
    u16* __restrict__ nodesB, u16* __restrict__ globB, u16* __restrict__ edgesB,
    const int* __restrict__ recv, const int* __restrict__ send,
    const int* __restrict__ ngi, const int* __restrict__ egi,
    float* __restrict__ out, int* __restrict__ zbase) {
    const int i = blockIdx.x * 256 + threadIdx.x;
    if (i < 114688) {
        if (i < 65536) {
            const int ch = i >> 15;
            const int r = i & 32767;
            const int row = r >> 9;
            const int inb = (r << 1) & 1023;
            const int kb = inb ^ ((row & 7) << 4);
            WeT2[i] = f2bf(We[(kb >> 1) * DD + ch * 64 + row]);
        } else {
            const int q = i - 65536;
            const int ch = q / 24576;
            const int r = q % 24576;
            const int row = r / 384;
            const int inb = (r % 384) << 1;
            const int kb = inb ^ ((row & 7) << 4);
            WnT2[q] = f2bf(Wn[(kb >> 1) * DD + ch * 64 + row]);
        }
    } else if (i < 647168) {
        const int j = i - 114688;
        const int NT = NODES_SZ / 8;
        if (j < NT) {
            const float4 a = *(const float4*)(nodes + (long)j * 8);
            const float4 b = *(const float4*)(nodes + (long)j * 8 + 4);
            *(short8*)(nodesB + (long)j * 8) = pack8(a, b);
        } else {
            const int j2 = j - NT;
            const float4 a = *(const float4*)(glob + (long)j2 * 8);
            const float4 b = *(const float4*)(glob + (long)j2 * 8 + 4);
            *(short8*)(globB + (long)j2 * 8) = pack8(a, b);
        }
    } else if (i < 2744320) {
        const long j = i - 647168;                  // < EDGES_SZ/8 = 2,097,152
        const float4 a = *(const float4*)(edges + j * 8);
        const float4 b = *(const float4*)(edges + j * 8 + 4);
        *(short8*)(edgesB + j * 8) = pack8(a, b);
    } else if (i < 3170304) {
        const int k2 = i - 2744320;
        if (k2 < BE_)                 out[OFF_RECV + k2] = (float)recv[k2];
        else if (k2 < 2 * BE_)        out[OFF_SEND + (k2 - BE_)] = (float)send[k2 - BE_];
        else if (k2 < 2 * BE_ + BN_)  out[OFF_NGI + (k2 - 2 * BE_)] = (float)ngi[k2 - 2 * BE_];
        else                          out[OFF_EGI + (k2 - 2 * BE_ - BN_)] = (float)egi[k2 - 2 * BE_ - BN_];
    } else {
        zbase[i - 3170304] = 0;                     // BN_ + 1024 ints
    }
}

__global__ __launch_bounds__(256) void k_hist_all(
    const int* __restrict__ recv, const int* __restrict__ egi,
    const int* __restrict__ ngi,
    int* __restrict__ cnt, int* __restrict__ gcnt_e, int* __restrict__ gcnt_n) {
    const int i = blockIdx.x * 256 + threadIdx.x;
    const int b = i >> 14;
    atomicAdd(&cnt[b * N_ + recv[i]], 1);
    atomicAdd(&gcnt_e[b * G_ + egi[i]], 1);
    if (i < BN_) atomicAdd(&gcnt_n[(i >> 12) * G_ + ngi[i]], 1);
}

__global__ __launch_bounds__(1024) void k_scan(
    const int* __restrict__ cnt, int* __restrict__ cur,
    const int* __restrict__ gcnt_e, int* __restrict__ gcur_e,
    const int* __restrict__ gcnt_n, int* __restrict__ gcur_n) {
    __shared__ int s[1024];
    const int b = blockIdx.x;
    const int t = threadIdx.x;
    const int base = b * N_;
    int c[4];
    int sum = 0;
    #pragma unroll
    for (int i = 0; i < 4; ++i) { c[i] = cnt[base + 4 * t + i]; sum += c[i]; }
    s[t] = sum;
    __syncthreads();
    for (int off = 1; off < 1024; off <<= 1) {
        int v = s[t];
        if (t >= off) v += s[t - off];
        __syncthreads();
        s[t] = v;
        __syncthreads();
    }
    int eb = s[t] - sum;
    #pragma unroll
    for (int i = 0; i < 4; ++i) { cur[base + 4 * t + i] = eb; eb += c[i]; }
    __syncthreads();
    int gv = 0;
    if (t < G_) { gv = gcnt_e[b * G_ + t]; s[t] = gv; }
    __syncthreads();
    for (int off = 1; off < G_; off <<= 1) {
        int v = 0;
        if (t < G_) { v = s[t]; if (t >= off) v += s[t - off]; }
        __syncthreads();
        if (t < G_) s[t] = v;
        __syncthreads();
    }
    if (t < G_) gcur_e[b * G_ + t] = s[t] - gv;
    __syncthreads();
    if (t < G_) { gv = gcnt_n[b * G_ + t]; s[t] = gv; }
    __syncthreads();
    for (int off = 1; off < G_; off <<= 1) {
        int v = 0;
        if (t < G_) { v = s[t]; if (t >= off) v += s[t - off]; }
        __syncthreads();
        if (t < G_) s[t] = v;
        __syncthreads();
    }
    if (t < G_) gcur_n[b * G_ + t] = s[t] - gv;
}

__global__ __launch_bounds__(256) void k_fill_all(
    const int* __restrict__ recv, const int* __restrict__ egi,
    const int* __restrict__ ngi,
    int* __restrict__ cur, int* __restrict__ elist,
    int* __restrict__ gcur_e, int* __restrict__ gelist_e,
    int* __restrict__ gcur_n, int* __restrict__ gelist_n) {
    const int i = blockIdx.x * 256 + threadIdx.x;
    const int b = i >> 14;
    const int s1 = atomicAdd(&cur[b * N_ + recv[i]], 1);
    elist[b * E_ + s1] = i;
    const int s2 = atomicAdd(&gcur_e[b * G_ + egi[i]], 1);
    gelist_e[b * E_ + s2] = i;
    if (i < BN_) {
        const int b2 = i >> 12;
        const int s3 = atomicAdd(&gcur_n[b2 * G_ + ngi[i]], 1);
        gelist_n[b2 * N_ + s3] = i;
    }
}

// -------- edge GEMM: 64 rows x 64 cols, all staging via global_load_lds ----
// LDS: Bs[64 cols][256 k-half u16]=32KB + As[64 rows][128 k-seg u16]=16KB.
__global__ __launch_bounds__(256, 3) void edge_mfma(
    const u16* __restrict__ edgesB, const u16* __restrict__ nodesB,
    const u16* __restrict__ globB,
    const int* __restrict__ receivers, const int* __restrict__ senders,
    const int* __restrict__ egi,
    const u16* __restrict__ WeT2, const float* __restrict__ be,
    const float* __restrict__ w_res,
    float* __restrict__ outE, u16* __restrict__ uEb) {
    __shared__ u16 Bs[64 * 256];               // 32 KB
    __shared__ u16 As[64 * 128];               // 16 KB
    const int tid = threadIdx.x;
    const int bid = blockIdx.x;                // 4096
    const int bb = bid & 7;                    // batch = XCD
    const int q = bid >> 3;                    // 0..511
    const int ch = q & 1;
    const int rt = q >> 1;                     // 0..255
    const int row0 = bb * E_ + rt * 64;

    const int wv = tid >> 6, l = tid & 63;
    const int fr = l & 15, fg = l >> 4;
    const int R = row0 + wv * 16 + fr;         // this lane's output row

    const char* img = (const char*)(WeT2 + (long)ch * 32768);

    // ---- staging helpers (all structural: global_load_lds, per-lane src) --
    auto stageB = [&](int half) {
        #pragma unroll
        for (int i = 0; i < 8; ++i) {
            const int col = wv * 16 + i * 2 + (l >> 5);
            const char* src = img + (long)col * 1024 + half * 512 + (l & 31) * 16;
            char* dst = (char*)Bs + (wv * 16 + i * 2) * 512;
            __builtin_amdgcn_global_load_lds(
                (const __attribute__((address_space(1))) void*)src,
                (__attribute__((address_space(3))) void*)dst, 16, 0, 0);
        }
    };
    auto stageA = [&](int seg) {
        #pragma unroll
        for (int i = 0; i < 4; ++i) {
            const int r = wv * 16 + i * 4 + (l >> 4);   // local row 0..63
            const int gr = row0 + r;                     // global edge row
            const u16* rp;
            if (seg == 0)      rp = edgesB + (long)gr * DD;
            else if (seg == 1) rp = nodesB + ((long)bb * N_ + senders[gr]) * DD;
            else if (seg == 2) rp = nodesB + ((long)bb * N_ + receivers[gr]) * DD;
            else               rp = globB + ((long)bb * G_ + egi[gr]) * DD;
            const char* src = (const char*)rp + (((l & 15) * 16) ^ ((r & 7) << 4));
            char* dst = (char*)As + (wv * 16 + i * 4) * 256;
            __builtin_amdgcn_global_load_lds(
                (const __attribute__((address_space(1))) void*)src,
                (__attribute__((address_space(3))) void*)dst, 16, 0, 0);
        }
    };

    f32x4 acc[4];
    const f32x4 fz = {0.f, 0.f, 0.f, 0.f};
    #pragma unroll
    for (int i = 0; i < 4; ++i) acc[i] = fz;

    const int lrow = wv * 16 + fr;
    const int swzA = (lrow & 7) << 4;
    const int swzB = (fr & 7) << 4;

    auto computeSeg = [&](int seg) {
        const int hb = (seg & 1) * 256;        // byte base within B half
        #pragma unroll
        for (int ss = 0; ss < 4; ++ss) {
            const short8 a = *(const short8*)(
                (char*)As + lrow * 256 + ((ss * 64 + fg * 16) ^ swzA));
            #pragma unroll
            for (int nt = 0; nt < 4; ++nt) {
                const short8 b = *(const short8*)(
                    (char*)Bs + (nt * 16 + fr) * 512 +
                    ((hb + ss * 64 + fg * 16) ^ swzB));
                acc[nt] = __builtin_amdgcn_mfma_f32_16x16x32_bf16(b, a, acc[nt], 0, 0, 0);
            }
        }
    };

    // ---- pipeline: stage -> drain(barrier) -> compute -> release(barrier) --
    stageB(0); stageA(0);
    __syncthreads();                           // vmcnt(0) drain
    computeSeg(0);
    // capture residual source (edges row R, cols c..c+3 per nt) from LDS seg0
    s16x4 eres[4];
    #pragma unroll
    for (int nt = 0; nt < 4; ++nt) {
        const int jb = ch * 128 + nt * 32 + fg * 8;   // byte offset = col*2
        eres[nt] = *(const s16x4*)((char*)As + lrow * 256 + (jb ^ swzA));
    }
    __syncthreads();                           // release As
    stageA(1);
    __syncthreads();
    computeSeg(1);
    __syncthreads();                           // release As + Bs
    stageA(2); stageB(1);
    __syncthreads();
    computeSeg(2);
    __syncthreads();
    stageA(3);
    __syncthreads();
    computeSeg(3);

    // ---- fused-residual epilogue: lane owns cols c..c+3 at row R ----------
    const float wr = w_res[0];
    #pragma unroll
    for (int nt = 0; nt < 4; ++nt) {
        const int c = ch * 64 + nt * 16 + fg * 4;
        const float4 bv = *(const float4*)(be + c);
        const float u0 = fmaxf(acc[nt][0] + bv.x, 0.f);
        const float u1 = fmaxf(acc[nt][1] + bv.y, 0.f);
        const float u2 = fmaxf(acc[nt][2] + bv.z, 0.f);
        const float u3 = fmaxf(acc[nt][3] + bv.w, 0.f);
        s16x4 h;
        h[0] = (short)f2bf(u0); h[1] = (short)f2bf(u1);
        h[2] = (short)f2bf(u2); h[3] = (short)f2bf(u3);
        *(s16x4*)(uEb + (long)R * DD + c) = h;
        float4 o;
        o.x = bf2f((u16)eres[nt][0]) + wr * u0;
        o.y = bf2f((u16)eres[nt][1]) + wr * u1;
        o.z = bf2f((u16)eres[nt][2]) + wr * u2;
        o.w = bf2f((u16)eres[nt][3]) + wr * u3;
        *(float4*)(outE + (long)R * DD + c) = o;
    }
}

// -------- adj = CSR gather-sum of bf16 u_e rows -> bf16 adjB --------
__global__ __launch_bounds__(256) void adj_gather(
    const int* __restrict__ cur, const int* __restrict__ cnt,
    const int* __restrict__ elist, const u16* __restrict__ uEb,
    u16* __restrict__ adjB) {
    const int tid = threadIdx.x;
    const int row = blockIdx.x * 64 + (tid >> 2);
    const int q = tid & 3;
    const int bb = row >> 12;
    const int deg = cnt[row];
    const int start = cur[row] - deg;
    const int* lp = elist + (long)bb * E_ + start;
    float a[32];
    #pragma unroll
    for (int j = 0; j < 32; ++j) a[j] = 0.f;
    for (int i = 0; i < deg; ++i) {
        const u16* up = uEb + (long)lp[i] * DD + q * 32;
        #pragma unroll
        for (int j = 0; j < 4; ++j) {
            const short8 v = *(const short8*)(up + j * 8);
            #pragma unroll
            for (int e2 = 0; e2 < 8; ++e2) a[j * 8 + e2] += bf2f((u16)v[e2]);
        }
    }
    u16* dst = adjB + (long)row * DD + q * 32;
    #pragma unroll
    for (int j = 0; j < 4; ++j) {
        short8 h;
        #pragma unroll
        for (int e2 = 0; e2 < 8; ++e2) h[e2] = (short)f2bf(a[j * 8 + e2]);
        *(short8*)(dst + j * 8) = h;
    }
}

// -------- agg = per-(b,g) gather-sum of bf16 u rows --------
__global__ __launch_bounds__(256) void agg_only(
    const int* __restrict__ gcnt, const int* __restrict__ gcur,
    const int* __restrict__ gelist, int spb, const u16* __restrict__ uB,
    float* __restrict__ aggp /* [PART][BG][DD] */) {
    __shared__ float accl[1024];
    const int bg = blockIdx.x >> 2;            // grid = BG*PART
    const int p  = blockIdx.x & 3;
    const int b = bg >> 6;
    const int tid = threadIdx.x;
    const int c4 = (tid & 31) << 2;
    const int sub = tid >> 5;                  // 0..7
    const int m = gcnt[bg];
    const int* lp = gelist + (long)b * spb + (gcur[bg] - m);
    f32x4 acc = {0.f, 0.f, 0.f, 0.f};
    for (int j = p * 8 + sub; j < m; j += 32) {
        const u16* up = uB + (long)lp[j] * DD + c4;
        const s16x4 v = *(const s16x4*)up;
        acc[0] += bf2f((u16)v[0]); acc[1] += bf2f((u16)v[1]);
        acc[2] += bf2f((u16)v[2]); acc[3] += bf2f((u16)v[3]);
    }
    *(f32x4*)&accl[sub * 128 + c4] = acc;
    __syncthreads();
    if (tid < 128) {
        float s = 0.f;
        #pragma unroll
        for (int q2 = 0; q2 < 8; ++q2) s += accl[q2 * 128 + tid];
        aggp[((long)p * BG_ + bg) * DD + tid] = s;
    }
}

// -------- node GEMM: R11 structure (B whole async-LDS), fused residual ----
__global__ __launch_bounds__(256, 3) void node_mfma(
    const u16* __restrict__ nodesB, const u16* __restrict__ adjB,
    const u16* __restrict__ globB, const int* __restrict__ ngi,
    const u16* __restrict__ WnT2, const float* __restrict__ bn,
    const float* __restrict__ nodes, const float* __restrict__ w_res,
    float* __restrict__ outN, u16* __restrict__ uNb) {
    __shared__ u16 Bs[64 * 384];               // 48 KB pre-swizzled B image
    const int tid = threadIdx.x;
    const int bid = blockIdx.x;                // 512
    const int bb = bid & 7;
    const int jj = bid >> 3;                   // 0..63
    const int ch = jj & 1;
    const int rt = jj >> 1;                    // 0..31
    const int row0 = bb * N_ + rt * 128;

    const int wv = tid >> 6, l = tid & 63;
    const int fr = l & 15, fg = l >> 4;
    const int rowbase = row0 + wv * 32;
    const int R0 = rowbase + fr, R1 = R0 + 16;

    {
        const char* wsrc = (const char*)(WnT2 + (long)ch * 24576) + l * 16;
        char* ldst = (char*)Bs;
        #pragma unroll
        for (int i2 = 0; i2 < 12; ++i2) {
            const int off = (wv * 12 + i2) * 1024;
            __builtin_amdgcn_global_load_lds(
                (const __attribute__((address_space(1))) void*)(wsrc + off),
                (__attribute__((address_space(3))) void*)(ldst + off),
                16, 0, 0);
        }
    }

    const u16* aps0[3] = { nodesB + (long)R0 * DD, adjB + (long)R0 * DD,
                           globB + ((long)bb * G_ + ngi[R0]) * DD };
    const u16* aps1[3] = { nodesB + (long)R1 * DD, adjB + (long)R1 * DD,
                           globB + ((long)bb * G_ + ngi[R1]) * DD };
    short8 P0[3][4], P1[3][4];
    #pragma unroll
    for (int s = 0; s < 3; ++s) {
        #pragma unroll
        for (int ss = 0; ss < 4; ++ss) {
            P0[s][ss] = *(const short8*)(aps0[s] + ss * 32 + fg * 8);
            P1[s][ss] = *(const short8*)(aps1[s] + ss * 32 + fg * 8);
        }
    }

    f32x4 acc0[4], acc1[4];
    const f32x4 fz = {0.f, 0.f, 0.f, 0.f};
    #pragma unroll
    for (int i = 0; i < 4; ++i) { acc0[i] = fz; acc1[i] = fz; }

    __syncthreads();

    const char* bsp = (const char*)Bs;
    const int swr = (fr & 7) << 4;
    #pragma unroll
    for (int seg = 0; seg < 3; ++seg) {
        #pragma unroll
        for (int ss = 0; ss < 4; ++ss) {
            short8 bfr[4];
            #pragma unroll
            for (int nt = 0; nt < 4; ++nt) {
                const int addr = (nt * 16 + fr) * 768 +
                                 ((seg * 256 + ss * 64 + fg * 16) ^ swr);
                bfr[nt] = *(const short8*)(bsp + addr);
            }
            #pragma unroll
            for (int nt = 0; nt < 4; ++nt) {
                acc0[nt] = __builtin_amdgcn_mfma_f32_16x16x32_bf16(bfr[nt], P0[seg][ss], acc0[nt], 0, 0, 0);
                acc1[nt] = __builtin_amdgcn_mfma_f32_16x16x32_bf16(bfr[nt], P1[seg][ss], acc1[nt], 0, 0, 0);
            }
        }
    }

    const float wr = w_res[0];
    #pragma unroll
    for (int nt = 0; nt < 4; ++nt) {
        const int c = ch * 64 + nt * 16 + fg * 4;
        const float4 bv = *(const float4*)(bn + c);
        const float4 n0 = *(const float4*)(nodes + (long)R0 * DD + c);
        const float4 n1 = *(const float4*)(nodes + (long)R1 * DD + c);
        const float u00 = fmaxf(acc0[nt][0] + bv.x, 0.f);
        const float u01 = fmaxf(acc0[nt][1] + bv.y, 0.f);
        const float u02 = fmaxf(acc0[nt][2] + bv.z, 0.f);
        const float u03 = fmaxf(acc0[nt][3] + bv.w, 0.f);
        const float u10 = fmaxf(acc1[nt][0] + bv.x, 0.f);
        const float u11 = fmaxf(acc1[nt][1] + bv.y, 0.f);
        const float u12 = fmaxf(acc1[nt][2] + bv.z, 0.f);
        const float u13 = fmaxf(acc1[nt][3] + bv.w, 0.f);
        s16x4 h0, h1;
        h0[0] = (short)f2bf(u00); h0[1] = (short)f2bf(u01);
        h0[2] = (short)f2bf(u02); h0[3] = (short)f2bf(u03);
        h1[0] = (short)f2bf(u10); h1[1] = (short)f2bf(u11);
        h1[2] = (short)f2bf(u12); h1[3] = (short)f2bf(u13);
        *(s16x4*)(uNb + (long)R0 * DD + c) = h0;
        *(s16x4*)(uNb + (long)R1 * DD + c) = h1;
        float4 o0, o1;
        o0.x = n0.x + wr * u00; o0.y = n0.y + wr * u01;
        o0.z = n0.z + wr * u02; o0.w = n0.w + wr * u03;
        o1.x = n1.x + wr * u10; o1.y = n1.y + wr * u11;
        o1.z = n1.z + wr * u12; o1.w = n1.w + wr * u13;
        *(float4*)(outN + (long)R0 * DD + c) = o0;
        *(float4*)(outN + (long)R1 * DD + c) = o1;
    }
}

// ---------------- global block: 512 rows, K=384, fp32 VALU ----------------
__global__ __launch_bounds__(128) void global_block(
    const float* __restrict__ naggp, const float* __restrict__ eaggp,
    const float* __restrict__ glob,
    const float* __restrict__ Wg, const float* __restrict__ bgb,
    const float* __restrict__ w_res, float* __restrict__ out) {
    __shared__ float gin[384];
    const int row = blockIdx.x;
    const int tid = threadIdx.x;
    float sn = 0.f, se = 0.f;
    #pragma unroll
    for (int p = 0; p < PART; ++p) {
        sn += naggp[((long)p * BG_ + row) * DD + tid];
        se += eaggp[((long)p * BG_ + row) * DD + tid];
    }
    gin[tid]       = sn;
    gin[128 + tid] = se;
    gin[256 + tid] = glob[row * DD + tid];
    __syncthreads();
    float acc = bgb[tid];
    #pragma unroll 4
    for (int k = 0; k < 384; ++k) acc += gin[k] * Wg[k * DD + tid];
    const float upd = fmaxf(acc, 0.f);
    out[OFF_GLOB + row * DD + tid] = glob[row * DD + tid] + w_res[0] * upd;
}

extern "C" void kernel_launch(void* const* d_in, const int* in_sizes, int n_in,
                              void* d_out, int out_size, void* d_ws, size_t ws_size,
                              hipStream_t stream) {
    const float* nodes     = (const float*)d_in[0];
    const float* edges     = (const float*)d_in[1];
    const int*   receivers = (const int*)d_in[2];
    const int*   senders   = (const int*)d_in[3];
    const float* glob      = (const float*)d_in[4];
    const int*   ngi       = (const int*)d_in[5];
    const int*   egi       = (const int*)d_in[6];
    const float* We        = (const float*)d_in[7];
    const float* be        = (const float*)d_in[8];
    const float* Wn        = (const float*)d_in[9];
    const float* bn        = (const float*)d_in[10];
    const float* Wg        = (const float*)d_in[11];
    const float* bg        = (const float*)d_in[12];
    const float* w_res     = (const float*)d_in[13];
    float* out = (float*)d_out;
    float* ws  = (float*)d_ws;

    float* eaggp = ws + WS_EAGGP;
    float* naggp = ws + WS_NAGGP;
    int* cnt      = (int*)(ws + WS_CNT);
    int* gcnt_e   = (int*)(ws + WS_GCNTE);
    int* gcnt_n   = (int*)(ws + WS_GCNTN);
    int* cur      = (int*)(ws + WS_CUR);
    int* gcur_e   = (int*)(ws + WS_GCURE);
    int* gcur_n   = (int*)(ws + WS_GCURN);
    int* elist    = (int*)(ws + WS_ELIST);
    int* gelist_e = (int*)(ws + WS_GELE);
    int* gelist_n = (int*)(ws + WS_GELN);
    u16* adjB   = (u16*)(ws + WS_ADJB);
    u16* nodesB = (u16*)(ws + WS_NODB);
    u16* globB  = (u16*)(ws + WS_GLOBB);
    u16* WeT2   = (u16*)(ws + WS_WET);
    u16* WnT2   = (u16*)(ws + WS_WNT);
    u16* uEb    = (u16*)(ws + WS_UEB);
    u16* edgesB = (u16*)(ws + WS_EDGB);
    u16* uNb    = uEb;               // aliases: uEb fully consumed first

    float* outE = out + OFF_EDGES;
    float* outN = out + OFF_NODES;

    hipLaunchKernelGGL(prep_all, dim3(12516), dim3(256), 0, stream,
                       We, Wn, WeT2, WnT2, nodes, glob, edges,
                       nodesB, globB, edgesB,
                       receivers, senders, ngi, egi, out, cnt);
    hipLaunchKernelGGL(k_hist_all, dim3(512), dim3(256), 0, stream,
                       receivers, egi, ngi, cnt, gcnt_e, gcnt_n);
    hipLaunchKernelGGL(k_scan, dim3(8), dim3(1024), 0, stream,
                       cnt, cur, gcnt_e, gcur_e, gcnt_n, gcur_n);
    hipLaunchKernelGGL(k_fill_all, dim3(512), dim3(256), 0, stream,
                       receivers, egi, ngi, cur, elist, gcur_e, gelist_e,
                       gcur_n, gelist_n);
    hipLaunchKernelGGL(edge_mfma, dim3(4096), dim3(256), 0, stream,
                       edgesB, nodesB, globB, receivers, senders, egi,
                       WeT2, be, w_res, outE, uEb);
    hipLaunchKernelGGL(adj_gather, dim3(BN_ / 64), dim3(256), 0, stream,
                       cur, cnt, elist, uEb, adjB);
    hipLaunchKernelGGL(agg_only, dim3(BG_ * PART), dim3(256), 0, stream,
                       gcnt_e, gcur_e, gelist_e, E_, uEb, eaggp);
    hipLaunchKernelGGL(node_mfma, dim3(512), dim3(256), 0, stream,
                       nodesB, adjB, globB, ngi, WnT2, bn, nodes, w_res,
                       outN, uNb);
    hipLaunchKernelGGL(agg_only, dim3(BG_ * PART), dim3(256), 0, stream,
                       gcnt_n, gcur_n, gelist_n, N_, uNb, naggp);
    hipLaunchKernelGGL(global_block, dim3(BG_), dim3(128), 0, stream,
                       naggp, eaggp, glob, Wg, bg, w_res, out);
}

// Round 13
// 224.629 us; speedup vs baseline: 1.1254x; 1.0038x over previous
//
#include <hip/hip_runtime.h>

// GraphNetworkLayer: B=8, N=4096, E=16384, G=64, D=128, fp32 in/out.
// Round 13:
//  - edge_mfma: M-rep 2 (block 128 rows x 64 cols, wave 32x64) cuts LDS
//    reads/MFMA 1.25 -> 0.75 (kernel was LDS-read-bound). Structural
//    global_load_lds staging kept (R12): As[128][256B] 32KB + per-seg
//    Bs[64][256B] 16KB = 48KB, 3 blocks/CU.
//  - node_mfma: adj folded in — seg-1 A frags built by in-kernel CSR
//    gather-sum of bf16 uEb rows; adj_gather kernel + adjB deleted.
//    uNb relocated to the (consumed) edgesB region.
// No float atomics anywhere.

#define DD 128
typedef unsigned short u16;
typedef __attribute__((ext_vector_type(8))) short short8;   // 8 bf16
typedef __attribute__((ext_vector_type(4))) short s16x4;    // 4 bf16
typedef __attribute__((ext_vector_type(4))) float f32x4;

constexpr int B_ = 8, N_ = 4096, E_ = 16384, G_ = 64;
constexpr int NODES_SZ = B_ * N_ * DD;   // 4,194,304
constexpr int EDGES_SZ = B_ * E_ * DD;   // 16,777,216
constexpr int BE_ = B_ * E_;             // 131,072
constexpr int BN_ = B_ * N_;             // 32,768
constexpr int BG_ = B_ * G_;             // 512
constexpr int GLOB_SZ = BG_ * DD;        // 65,536
constexpr int PART = 4;

constexpr int OFF_NODES = 0;
constexpr int OFF_EDGES = OFF_NODES + NODES_SZ;
constexpr int OFF_RECV  = OFF_EDGES + EDGES_SZ;
constexpr int OFF_SEND  = OFF_RECV + BE_;
constexpr int OFF_GLOB  = OFF_SEND + BE_;
constexpr int OFF_NGI   = OFF_GLOB + GLOB_SZ;
constexpr int OFF_EGI   = OFF_NGI + BN_;

// ws layout (float-element offsets)
constexpr int WS_EAGGP = 0;                          // [PART][BG][DD] f32
constexpr int WS_NAGGP = WS_EAGGP + PART * GLOB_SZ;
constexpr int WS_CNT   = WS_NAGGP + PART * GLOB_SZ;  // int [B*N] (zeroed)
constexpr int WS_GCNTE = WS_CNT + BN_;               // int [512] (zeroed)
constexpr int WS_GCNTN = WS_GCNTE + 512;             // int [512] (zeroed)
constexpr int WS_CUR   = WS_GCNTN + 512;             // int [B*N]
constexpr int WS_GCURE = WS_CUR + BN_;               // int [512]
constexpr int WS_GCURN = WS_GCURE + 512;             // int [512]
constexpr int WS_ELIST = WS_GCURN + 512;             // int [B*E]
constexpr int WS_GELE  = WS_ELIST + BE_;             // int [B*E]
constexpr int WS_GELN  = WS_GELE + BE_;              // int [B*N]
constexpr int WS_ADJB  = WS_GELN + BN_;              // (unused this round)
constexpr int WS_NODB  = WS_ADJB + (BN_ * DD) / 2;   // u16 [B,N,D]
constexpr int WS_GLOBB = WS_NODB + (BN_ * DD) / 2;   // u16 [B,G,D]
constexpr int WS_WET   = WS_GLOBB + GLOB_SZ / 2;     // u16 [128*512] swz image
constexpr int WS_WNT   = WS_WET + 32768;             // u16 [128*384] swz image
constexpr int WS_UEB   = WS_WNT + 24576;             // u16 [B,E,D] bf16 u_e
constexpr int WS_EDGB  = WS_UEB + (BE_ * DD) / 2;    // u16 [B,E,D] edgesB; uNb after

__device__ inline u16 f2bf(float f) {
    union { float f; unsigned u; } v; v.f = f;
    return (u16)((v.u + 0x7fffu + ((v.u >> 16) & 1u)) >> 16);
}
__device__ inline float bf2f(u16 h) {
    union { unsigned u; float f; } v; v.u = ((unsigned)h) << 16; return v.f;
}
__device__ inline short8 pack8(float4 a, float4 b) {
    short8 r;
    r[0] = (short)f2bf(a.x); r[1] = (short)f2bf(a.y);
    r[2] = (short)f2bf(a.z); r[3] = (short)f2bf(a.w);
    r[4] = (short)f2bf(b.x); r[5] = (short)f2bf(b.y);
    r[6] = (short)f2bf(b.z); r[7] = (short)f2bf(b.w);
    return r;
}

// -------- fused prep (R12, unchanged) --------
__global__ __launch_bounds__(256) void prep_all(
    const float* __restrict__ We, const float* __restrict__ Wn,
    u16* __restrict__ WeT2, u16* __restrict__ WnT2,
    const float* __restrict__ nodes, const float* __restrict__ glob,
    const float* __restrict__ edges,
    u16* __restrict__ nodesB, u16* __restrict__ globB, u16* __restrict__ edgesB,
    const int* __restrict__ recv, const int* __restrict__ send,
    const int* __restrict__ ngi, const int* __restrict__ egi,
    float* __restrict__ out, int* __restrict__ zbase) {
    const int i = blockIdx.x * 256 + threadIdx.x;
    if (i < 114688) {
        if (i < 65536) {
            const int ch = i >> 15;
            const int r = i & 32767;
            const int row = r >> 9;
            const int inb = (r << 1) & 1023;
            const int kb = inb ^ ((row & 7) << 4);
            WeT2[i] = f2bf(We[(kb >> 1) * DD + ch * 64 + row]);
        } else {
            const int q = i - 65536;
            const int ch = q / 24576;
            const int r = q % 24576;
            const int row = r / 384;
            const int inb = (r % 384) << 1;
            const int kb = inb ^ ((row & 7) << 4);
            WnT2[q] = f2bf(Wn[(kb >> 1) * DD + ch * 64 + row]);
        }
    } else if (i < 647168) {
        const int j = i - 114688;
        const int NT = NODES_SZ / 8;
        if (j < NT) {
            const float4 a = *(const float4*)(nodes + (long)j * 8);
            const float4 b = *(const float4*)(nodes + (long)j * 8 + 4);
            *(short8*)(nodesB + (long)j * 8) = pack8(a, b);
        } else {
            const int j2 = j - NT;
            const float4 a = *(const float4*)(glob + (long)j2 * 8);
            const float4 b = *(const float4*)(glob + (long)j2 * 8 + 4);
            *(short8*)(globB + (long)j2 * 8) = pack8(a, b);
        }
    } else if (i < 2744320) {
        const long j = i - 647168;                  // < EDGES_SZ/8
        const float4 a = *(const float4*)(edges + j * 8);
        const float4 b = *(const float4*)(edges + j * 8 + 4);
        *(short8*)(edgesB + j * 8) = pack8(a, b);
    } else if (i < 3170304) {
        const int k2 = i - 2744320;
        if (k2 < BE_)                 out[OFF_RECV + k2] = (float)recv[k2];
        else if (k2 < 2 * BE_)        out[OFF_SEND + (k2 - BE_)] = (float)send[k2 - BE_];
        else if (k2 < 2 * BE_ + BN_)  out[OFF_NGI + (k2 - 2 * BE_)] = (float)ngi[k2 - 2 * BE_];
        else                          out[OFF_EGI + (k2 - 2 * BE_ - BN_)] = (float)egi[k2 - 2 * BE_ - BN_];
    } else {
        zbase[i - 3170304] = 0;                     // BN_ + 1024 ints
    }
}

__global__ __launch_bounds__(256) void k_hist_all(
    const int* __restrict__ recv, const int* __restrict__ egi,
    const int* __restrict__ ngi,
    int* __restrict__ cnt, int* __restrict__ gcnt_e, int* __restrict__ gcnt_n) {
    const int i = blockIdx.x * 256 + threadIdx.x;
    const int b = i >> 14;
    atomicAdd(&cnt[b * N_ + recv[i]], 1);
    atomicAdd(&gcnt_e[b * G_ + egi[i]], 1);
    if (i < BN_) atomicAdd(&gcnt_n[(i >> 12) * G_ + ngi[i]], 1);
}

__global__ __launch_bounds__(1024) void k_scan(
    const int* __restrict__ cnt, int* __restrict__ cur,
    const int* __restrict__ gcnt_e, int* __restrict__ gcur_e,
    const int* __restrict__ gcnt_n, int* __restrict__ gcur_n) {
    __shared__ int s[1024];
    const int b = blockIdx.x;
    const int t = threadIdx.x;
    const int base = b * N_;
    int c[4];
    int sum = 0;
    #pragma unroll
    for (int i = 0; i < 4; ++i) { c[i] = cnt[base + 4 * t + i]; sum += c[i]; }
    s[t] = sum;
    __syncthreads();
    for (int off = 1; off < 1024; off <<= 1) {
        int v = s[t];
        if (t >= off) v += s[t - off];
        __syncthreads();
        s[t] = v;
        __syncthreads();
    }
    int eb = s[t] - sum;
    #pragma unroll
    for (int i = 0; i < 4; ++i) { cur[base + 4 * t + i] = eb; eb += c[i]; }
    __syncthreads();
    int gv = 0;
    if (t < G_) { gv = gcnt_e[b * G_ + t]; s[t] = gv; }
    __syncthreads();
    for (int off = 1; off < G_; off <<= 1) {
        int v = 0;
        if (t < G_) { v = s[t]; if (t >= off) v += s[t - off]; }
        __syncthreads();
        if (t < G_) s[t] = v;
        __syncthreads();
    }
    if (t < G_) gcur_e[b * G_ + t] = s[t] - gv;
    __syncthreads();
    if (t < G_) { gv = gcnt_n[b * G_ + t]; s[t] = gv; }
    __syncthreads();
    for (int off = 1; off < G_; off <<= 1) {
        int v = 0;
        if (t < G_) { v = s[t]; if (t >= off) v += s[t - off]; }
        __syncthreads();
        if (t < G_) s[t] = v;
        __syncthreads();
    }
    if (t < G_) gcur_n[b * G_ + t] = s[t] - gv;
}

__global__ __launch_bounds__(256) void k_fill_all(
    const int* __restrict__ recv, const int* __restrict__ egi,
    const int* __restrict__ ngi,
    int* __restrict__ cur, int* __restrict__ elist,
    int* __restrict__ gcur_e, int* __restrict__ gelist_e,
    int* __restrict__ gcur_n, int* __restrict__ gelist_n) {
    const int i = blockIdx.x * 256 + threadIdx.x;
    const int b = i >> 14;
    const int s1 = atomicAdd(&cur[b * N_ + recv[i]], 1);
    elist[b * E_ + s1] = i;
    const int s2 = atomicAdd(&gcur_e[b * G_ + egi[i]], 1);
    gelist_e[b * E_ + s2] = i;
    if (i < BN_) {
        const int b2 = i >> 12;
        const int s3 = atomicAdd(&gcur_n[b2 * G_ + ngi[i]], 1);
        gelist_n[b2 * N_ + s3] = i;
    }
}

// -------- edge GEMM: 128 rows x 64 cols, M-rep 2, structural staging ------
__global__ __launch_bounds__(256, 3) void edge_mfma(
    const u16* __restrict__ edgesB, const u16* __restrict__ nodesB,
    const u16* __restrict__ globB,
    const int* __restrict__ receivers, const int* __restrict__ senders,
    const int* __restrict__ egi,
    const u16* __restrict__ WeT2, const float* __restrict__ be,
    const float* __restrict__ w_res,
    float* __restrict__ outE, u16* __restrict__ uEb) {
    __shared__ u16 As[128 * 128];              // 32 KB: 128 rows x 256B
    __shared__ u16 Bs[64 * 128];               // 16 KB: 64 cols x 256B (1 seg)
    const int tid = threadIdx.x;
    const int bid = blockIdx.x;                // 2048
    const int bb = bid & 7;                    // batch = XCD
    const int q = bid >> 3;                    // 0..255
    const int ch = q & 1;
    const int rt = q >> 1;                     // 0..127
    const int row0 = bb * E_ + rt * 128;

    const int wv = tid >> 6, l = tid & 63;
    const int fr = l & 15, fg = l >> 4;
    const int lrow0 = wv * 32 + fr;
    const int R0 = row0 + lrow0, R1 = R0 + 16;

    const char* img = (const char*)(WeT2 + (long)ch * 32768);
    const int swz = (fr & 7) << 4;

    f32x4 acc0[4], acc1[4];
    const f32x4 fz = {0.f, 0.f, 0.f, 0.f};
    #pragma unroll
    for (int i = 0; i < 4; ++i) { acc0[i] = fz; acc1[i] = fz; }
    s16x4 eres0[4], eres1[4];

    #pragma unroll
    for (int seg = 0; seg < 4; ++seg) {
        // stage A(seg): 8 insts/thread, per-lane pre-swizzled source
        #pragma unroll
        for (int i = 0; i < 8; ++i) {
            const int r = wv * 32 + i * 4 + (l >> 4);
            const int gr = row0 + r;
            const u16* rp;
            if (seg == 0)      rp = edgesB + (long)gr * DD;
            else if (seg == 1) rp = nodesB + ((long)bb * N_ + senders[gr]) * DD;
            else if (seg == 2) rp = nodesB + ((long)bb * N_ + receivers[gr]) * DD;
            else               rp = globB + ((long)bb * G_ + egi[gr]) * DD;
            const char* src = (const char*)rp + (((l & 15) * 16) ^ ((r & 7) << 4));
            char* dst = (char*)As + (wv * 32 + i * 4) * 256;
            __builtin_amdgcn_global_load_lds(
                (const __attribute__((address_space(1))) void*)src,
                (__attribute__((address_space(3))) void*)dst, 16, 0, 0);
        }
        // stage B(seg): 4 insts/thread from pre-swizzled image
        #pragma unroll
        for (int i = 0; i < 4; ++i) {
            const int colbase = wv * 16 + i * 4;
            const char* src = img + (long)(colbase + (l >> 4)) * 1024 +
                              seg * 256 + (l & 15) * 16;
            char* dst = (char*)Bs + colbase * 256;
            __builtin_amdgcn_global_load_lds(
                (const __attribute__((address_space(1))) void*)src,
                (__attribute__((address_space(3))) void*)dst, 16, 0, 0);
        }
        __syncthreads();                       // vmcnt(0) drain
        __builtin_amdgcn_s_setprio(1);
        #pragma unroll
        for (int ss = 0; ss < 4; ++ss) {
            const int ko = (ss * 64 + fg * 16) ^ swz;
            const short8 a0 = *(const short8*)((char*)As + lrow0 * 256 + ko);
            const short8 a1 = *(const short8*)((char*)As + (lrow0 + 16) * 256 + ko);
            #pragma unroll
            for (int nt = 0; nt < 4; ++nt) {
                const short8 b = *(const short8*)((char*)Bs + (nt * 16 + fr) * 256 + ko);
                acc0[nt] = __builtin_amdgcn_mfma_f32_16x16x32_bf16(b, a0, acc0[nt], 0, 0, 0);
                acc1[nt] = __builtin_amdgcn_mfma_f32_16x16x32_bf16(b, a1, acc1[nt], 0, 0, 0);
            }
        }
        __builtin_amdgcn_s_setprio(0);
        if (seg == 0) {
            // residual source (edges values) from As before release
            #pragma unroll
            for (int nt = 0; nt < 4; ++nt) {
                const int jb = (ch * 128 + nt * 32 + fg * 8) ^ swz;
                eres0[nt] = *(const s16x4*)((char*)As + lrow0 * 256 + jb);
                eres1[nt] = *(const s16x4*)((char*)As + (lrow0 + 16) * 256 + jb);
            }
        }
        __syncthreads();                       // release As/Bs for next seg
    }

    // fused-residual epilogue
    const float wr = w_res[0];
    #pragma unroll
    for (int nt = 0; nt < 4; ++nt) {
        const int c = ch * 64 + nt * 16 + fg * 4;
        const float4 bv = *(const float4*)(be + c);
        const float u00 = fmaxf(acc0[nt][0] + bv.x, 0.f);
        const float u01 = fmaxf(acc0[nt][1] + bv.y, 0.f);
        const float u02 = fmaxf(acc0[nt][2] + bv.z, 0.f);
        const float u03 = fmaxf(acc0[nt][3] + bv.w, 0.f);
        const float u10 = fmaxf(acc1[nt][0] + bv.x, 0.f);
        const float u11 = fmaxf(acc1[nt][1] + bv.y, 0.f);
        const float u12 = fmaxf(acc1[nt][2] + bv.z, 0.f);
        const float u13 = fmaxf(acc1[nt][3] + bv.w, 0.f);
        s16x4 h0, h1;
        h0[0] = (short)f2bf(u00); h0[1] = (short)f2bf(u01);
        h0[2] = (short)f2bf(u02); h0[3] = (short)f2bf(u03);
        h1[0] = (short)f2bf(u10); h1[1] = (short)f2bf(u11);
        h1[2] = (short)f2bf(u12); h1[3] = (short)f2bf(u13);
        *(s16x4*)(uEb + (long)R0 * DD + c) = h0;
        *(s16x4*)(uEb + (long)R1 * DD + c) = h1;
        float4 o0, o1;
        o0.x = bf2f((u16)eres0[nt][0]) + wr * u00;
        o0.y = bf2f((u16)eres0[nt][1]) + wr * u01;
        o0.z = bf2f((u16)eres0[nt][2]) + wr * u02;
        o0.w = bf2f((u16)eres0[nt][3]) + wr * u03;
        o1.x = bf2f((u16)eres1[nt][0]) + wr * u10;
        o1.y = bf2f((u16)eres1[nt][1]) + wr * u11;
        o1.z = bf2f((u16)eres1[nt][2]) + wr * u12;
        o1.w = bf2f((u16)eres1[nt][3]) + wr * u13;
        *(float4*)(outE + (long)R0 * DD + c) = o0;
        *(float4*)(outE + (long)R1 * DD + c) = o1;
    }
}

// -------- agg = per-(b,g) gather-sum of bf16 u rows --------
__global__ __launch_bounds__(256) void agg_only(
    const int* __restrict__ gcnt, const int* __restrict__ gcur,
    const int* __restrict__ gelist, int spb, const u16* __restrict__ uB,
    float* __restrict__ aggp /* [PART][BG][DD] */) {
    __shared__ float accl[1024];
    const int bg = blockIdx.x >> 2;            // grid = BG*PART
    const int p  = blockIdx.x & 3;
    const int b = bg >> 6;
    const int tid = threadIdx.x;
    const int c4 = (tid & 31) << 2;
    const int sub = tid >> 5;                  // 0..7
    const int m = gcnt[bg];
    const int* lp = gelist + (long)b * spb + (gcur[bg] - m);
    f32x4 acc = {0.f, 0.f, 0.f, 0.f};
    for (int j = p * 8 + sub; j < m; j += 32) {
        const u16* up = uB + (long)lp[j] * DD + c4;
        const s16x4 v = *(const s16x4*)up;
        acc[0] += bf2f((u16)v[0]); acc[1] += bf2f((u16)v[1]);
        acc[2] += bf2f((u16)v[2]); acc[3] += bf2f((u16)v[3]);
    }
    *(f32x4*)&accl[sub * 128 + c4] = acc;
    __syncthreads();
    if (tid < 128) {
        float s = 0.f;
        #pragma unroll
        for (int q2 = 0; q2 < 8; ++q2) s += accl[q2 * 128 + tid];
        aggp[((long)p * BG_ + bg) * DD + tid] = s;
    }
}

// -------- node GEMM: adj folded in via CSR gather of uEb; fused residual --
__global__ __launch_bounds__(256, 3) void node_mfma(
    const u16* __restrict__ nodesB, const u16* __restrict__ uEb,
    const u16* __restrict__ globB, const int* __restrict__ ngi,
    const int* __restrict__ cnt, const int* __restrict__ cur,
    const int* __restrict__ elist,
    const u16* __restrict__ WnT2, const float* __restrict__ bn,
    const float* __restrict__ nodes, const float* __restrict__ w_res,
    float* __restrict__ outN, u16* __restrict__ uNb) {
    __shared__ u16 Bs[64 * 384];               // 48 KB pre-swizzled B image
    const int tid = threadIdx.x;
    const int bid = blockIdx.x;                // 512
    const int bb = bid & 7;
    const int jj = bid >> 3;                   // 0..63
    const int ch = jj & 1;
    const int rt = jj >> 1;                    // 0..31
    const int row0 = bb * N_ + rt * 128;

    const int wv = tid >> 6, l = tid & 63;
    const int fr = l & 15, fg = l >> 4;
    const int rowbase = row0 + wv * 32;
    const int R0 = rowbase + fr, R1 = R0 + 16;

    {
        const char* wsrc = (const char*)(WnT2 + (long)ch * 24576) + l * 16;
        char* ldst = (char*)Bs;
        #pragma unroll
        for (int i2 = 0; i2 < 12; ++i2) {
            const int off = (wv * 12 + i2) * 1024;
            __builtin_amdgcn_global_load_lds(
                (const __attribute__((address_space(1))) void*)(wsrc + off),
                (__attribute__((address_space(3))) void*)(ldst + off),
                16, 0, 0);
        }
    }

    // seg0 (nodes) and seg2 (glob) A frags
    const u16* pN0 = nodesB + (long)R0 * DD;
    const u16* pN1 = nodesB + (long)R1 * DD;
    const u16* pG0 = globB + ((long)bb * G_ + ngi[R0]) * DD;
    const u16* pG1 = globB + ((long)bb * G_ + ngi[R1]) * DD;
    short8 PN0[4], PN1[4], PG0[4], PG1[4], PA0[4], PA1[4];
    #pragma unroll
    for (int ss = 0; ss < 4; ++ss) {
        PN0[ss] = *(const short8*)(pN0 + ss * 32 + fg * 8);
        PN1[ss] = *(const short8*)(pN1 + ss * 32 + fg * 8);
        PG0[ss] = *(const short8*)(pG0 + ss * 32 + fg * 8);
        PG1[ss] = *(const short8*)(pG1 + ss * 32 + fg * 8);
    }

    // seg1 (adj) via CSR gather-sum of uEb rows, row-sequential (caps VGPR)
    {
        float ga[32];
        const int deg0 = cnt[R0];
        const int* lp0 = elist + (long)bb * E_ + (cur[R0] - deg0);
        #pragma unroll
        for (int j = 0; j < 32; ++j) ga[j] = 0.f;
        for (int i = 0; i < deg0; ++i) {
            const u16* up = uEb + (long)lp0[i] * DD + fg * 8;
            #pragma unroll
            for (int ss = 0; ss < 4; ++ss) {
                const short8 v = *(const short8*)(up + ss * 32);
                #pragma unroll
                for (int e2 = 0; e2 < 8; ++e2) ga[ss * 8 + e2] += bf2f((u16)v[e2]);
            }
        }
        #pragma unroll
        for (int ss = 0; ss < 4; ++ss) {
            short8 h;
            #pragma unroll
            for (int e2 = 0; e2 < 8; ++e2) h[e2] = (short)f2bf(ga[ss * 8 + e2]);
            PA0[ss] = h;
        }
        const int deg1 = cnt[R1];
        const int* lp1 = elist + (long)bb * E_ + (cur[R1] - deg1);
        #pragma unroll
        for (int j = 0; j < 32; ++j) ga[j] = 0.f;
        for (int i = 0; i < deg1; ++i) {
            const u16* up = uEb + (long)lp1[i] * DD + fg * 8;
            #pragma unroll
            for (int ss = 0; ss < 4; ++ss) {
                const short8 v = *(const short8*)(up + ss * 32);
                #pragma unroll
                for (int e2 = 0; e2 < 8; ++e2) ga[ss * 8 + e2] += bf2f((u16)v[e2]);
            }
        }
        #pragma unroll
        for (int ss = 0; ss < 4; ++ss) {
            short8 h;
            #pragma unroll
            for (int e2 = 0; e2 < 8; ++e2) h[e2] = (short)f2bf(ga[ss * 8 + e2]);
            PA1[ss] = h;
        }
    }

    f32x4 acc0[4], acc1[4];
    const f32x4 fz = {0.f, 0.f, 0.f, 0.f};
    #pragma unroll
    for (int i = 0; i < 4; ++i) { acc0[i] = fz; acc1[i] = fz; }

    __syncthreads();

    const char* bsp = (const char*)Bs;
    const int swr = (fr & 7) << 4;
    #pragma unroll
    for (int seg = 0; seg < 3; ++seg) {
        __builtin_amdgcn_s_setprio(1);
        #pragma unroll
        for (int ss = 0; ss < 4; ++ss) {
            const short8 a0 = (seg == 0) ? PN0[ss] : (seg == 1) ? PA0[ss] : PG0[ss];
            const short8 a1 = (seg == 0) ? PN1[ss] : (seg == 1) ? PA1[ss] : PG1[ss];
            #pragma unroll
            for (int nt = 0; nt < 4; ++nt) {
                const int addr = (nt * 16 + fr) * 768 +
                                 ((seg * 256 + ss * 64 + fg * 16) ^ swr);
                const short8 b = *(const short8*)(bsp + addr);
                acc0[nt] = __builtin_amdgcn_mfma_f32_16x16x32_bf16(b, a0, acc0[nt], 0, 0, 0);
                acc1[nt] = __builtin_amdgcn_mfma_f32_16x16x32_bf16(b, a1, acc1[nt], 0, 0, 0);
            }
        }
        __builtin_amdgcn_s_setprio(0);
    }

    const float wr = w_res[0];
    #pragma unroll
    for (int nt = 0; nt < 4; ++nt) {
        const int c = ch * 64 + nt * 16 + fg * 4;
        const float4 bv = *(const float4*)(bn + c);
        const float4 n0 = *(const float4*)(nodes + (long)R0 * DD + c);
        const float4 n1 = *(const float4*)(nodes + (long)R1 * DD + c);
        const float u00 = fmaxf(acc0[nt][0] + bv.x, 0.f);
        const float u01 = fmaxf(acc0[nt][1] + bv.y, 0.f);
        const float u02 = fmaxf(acc0[nt][2] + bv.z, 0.f);
        const float u03 = fmaxf(acc0[nt][3] + bv.w, 0.f);
        const float u10 = fmaxf(acc1[nt][0] + bv.x, 0.f);
        const float u11 = fmaxf(acc1[nt][1] + bv.y, 0.f);
        const float u12 = fmaxf(acc1[nt][2] + bv.z, 0.f);
        const float u13 = fmaxf(acc1[nt][3] + bv.w, 0.f);
        s16x4 h0, h1;
        h0[0] = (short)f2bf(u00); h0[1] = (short)f2bf(u01);
        h0[2] = (short)f2bf(u02); h0[3] = (short)f2bf(u03);
        h1[0] = (short)f2bf(u10); h1[1] = (short)f2bf(u11);
        h1[2] = (short)f2bf(u12); h1[3] = (short)f2bf(u13);
        *(s16x4*)(uNb + (long)R0 * DD + c) = h0;
        *(s16x4*)(uNb + (long)R1 * DD + c) = h1;
        float4 o0, o1;
        o0.x = n0.x + wr * u00; o0.y = n0.y + wr * u01;
        o0.z = n0.z + wr * u02; o0.w = n0.w + wr * u03;
        o1.x = n1.x + wr * u10; o1.y = n1.y + wr * u11;
        o1.z = n1.z + wr * u12; o1.w = n1.w + wr * u13;
        *(float4*)(outN + (long)R0 * DD + c) = o0;
        *(float4*)(outN + (long)R1 * DD + c) = o1;
    }
}

// ---------------- global block: 512 rows, K=384, fp32 VALU ----------------
__global__ __launch_bounds__(128) void global_block(
    const float* __restrict__ naggp, const float* __restrict__ eaggp,
    const float* __restrict__ glob,
    const float* __restrict__ Wg, const float* __restrict__ bgb,
    const float* __restrict__ w_res, float* __restrict__ out) {
    __shared__ float gin[384];
    const int row = blockIdx.x;
    const int tid = threadIdx.x;
    float sn = 0.f, se = 0.f;
    #pragma unroll
    for (int p = 0; p < PART; ++p) {
        sn += naggp[((long)p * BG_ + row) * DD + tid];
        se += eaggp[((long)p * BG_ + row) * DD + tid];
    }
    gin[tid]       = sn;
    gin[128 + tid] = se;
    gin[256 + tid] = glob[row * DD + tid];
    __syncthreads();
    float acc = bgb[tid];
    #pragma unroll 4
    for (int k = 0; k < 384; ++k) acc += gin[k] * Wg[k * DD + tid];
    const float upd = fmaxf(acc, 0.f);
    out[OFF_GLOB + row * DD + tid] = glob[row * DD + tid] + w_res[0] * upd;
}

extern "C" void kernel_launch(void* const* d_in, const int* in_sizes, int n_in,
                              void* d_out, int out_size, void* d_ws, size_t ws_size,
                              hipStream_t stream) {
    const float* nodes     = (const float*)d_in[0];
    const float* edges     = (const float*)d_in[1];
    const int*   receivers = (const int*)d_in[2];
    const int*   senders   = (const int*)d_in[3];
    const float* glob      = (const float*)d_in[4];
    const int*   ngi       = (const int*)d_in[5];
    const int*   egi       = (const int*)d_in[6];
    const float* We        = (const float*)d_in[7];
    const float* be        = (const float*)d_in[8];
    const float* Wn        = (const float*)d_in[9];
    const float* bn        = (const float*)d_in[10];
    const float* Wg        = (const float*)d_in[11];
    const float* bg        = (const float*)d_in[12];
    const float* w_res     = (const float*)d_in[13];
    float* out = (float*)d_out;
    float* ws  = (float*)d_ws;

    float* eaggp = ws + WS_EAGGP;
    float* naggp = ws + WS_NAGGP;
    int* cnt      = (int*)(ws + WS_CNT);
    int* gcnt_e   = (int*)(ws + WS_GCNTE);
    int* gcnt_n   = (int*)(ws + WS_GCNTN);
    int* cur      = (int*)(ws + WS_CUR);
    int* gcur_e   = (int*)(ws + WS_GCURE);
    int* gcur_n   = (int*)(ws + WS_GCURN);
    int* elist    = (int*)(ws + WS_ELIST);
    int* gelist_e = (int*)(ws + WS_GELE);
    int* gelist_n = (int*)(ws + WS_GELN);
    u16* nodesB = (u16*)(ws + WS_NODB);
    u16* globB  = (u16*)(ws + WS_GLOBB);
    u16* WeT2   = (u16*)(ws + WS_WET);
    u16* WnT2   = (u16*)(ws + WS_WNT);
    u16* uEb    = (u16*)(ws + WS_UEB);
    u16* edgesB = (u16*)(ws + WS_EDGB);
    u16* uNb    = (u16*)(ws + WS_EDGB);  // reuses edgesB region (consumed)

    float* outE = out + OFF_EDGES;
    float* outN = out + OFF_NODES;

    hipLaunchKernelGGL(prep_all, dim3(12516), dim3(256), 0, stream,
                       We, Wn, WeT2, WnT2, nodes, glob, edges,
                       nodesB, globB, edgesB,
                       receivers, senders, ngi, egi, out, cnt);
    hipLaunchKernelGGL(k_hist_all, dim3(512), dim3(256), 0, stream,
                       receivers, egi, ngi, cnt, gcnt_e, gcnt_n);
    hipLaunchKernelGGL(k_scan, dim3(8), dim3(1024), 0, stream,
                       cnt, cur, gcnt_e, gcur_e, gcnt_n, gcur_n);
    hipLaunchKernelGGL(k_fill_all, dim3(512), dim3(256), 0, stream,
                       receivers, egi, ngi, cur, elist, gcur_e, gelist_e,
                       gcur_n, gelist_n);
    hipLaunchKernelGGL(edge_mfma, dim3(2048), dim3(256), 0, stream,
                       edgesB, nodesB, globB, receivers, senders, egi,
                       WeT2, be, w_res, outE, uEb);
    hipLaunchKernelGGL(agg_only, dim3(BG_ * PART), dim3(256), 0, stream,
                       gcnt_e, gcur_e, gelist_e, E_, uEb, eaggp);
    hipLaunchKernelGGL(node_mfma, dim3(512), dim3(256), 0, stream,
                       nodesB, uEb, globB, ngi, cnt, cur, elist,
                       WnT2, bn, nodes, w_res, outN, uNb);
    hipLaunchKernelGGL(agg_only, dim3(BG_ * PART), dim3(256), 0, stream,
                       gcnt_n, gcur_n, gelist_n, N_, uNb, naggp);
    hipLaunchKernelGGL(global_block, dim3(BG_), dim3(128), 0, stream,
                       naggp, eaggp, glob, Wg, bg, w_res, out);
}